// Round 1
// baseline (429.709 us; speedup 1.0000x reference)
//
#include <hip/hip_runtime.h>
#include <cstdint>

// Problem constants (fixed by the reference)
#define N_SEQ 4096
#define DMODEL 1024

#define BM 128
#define BN 128
#define BK 32

typedef __bf16 bf16_t;
typedef bf16_t bf16x8 __attribute__((ext_vector_type(8)));
typedef bf16_t bf16x4 __attribute__((ext_vector_type(4)));
typedef float f32x4 __attribute__((ext_vector_type(4)));

typedef __attribute__((address_space(1))) void* as1ptr;
typedef __attribute__((address_space(3))) void* as3ptr;

__device__ __forceinline__ void gload16(const bf16_t* g, bf16_t* l) {
  __builtin_amdgcn_global_load_lds((as1ptr)(uintptr_t)g, (as3ptr)(uintptr_t)l,
                                   16, 0, 0);
}

enum { EPI_F32 = 0, EPI_HILO = 1, EPI_BF16T = 2, EPI_BF16 = 3 };

// C[M,Nc] = (Ahi+Alo)[M,K] @ (Bhi+Blo)[Nc,K]^T  (+ bias[col])
// PASSES==3: hi*hi + hi*lo + lo*hi (fp32-ish precision)
// PASSES==1: hi*hi only
template <int PASSES, int EPI>
__global__ __launch_bounds__(256)
void gemm_bt(const bf16_t* __restrict__ Ahi, const bf16_t* __restrict__ Alo,
             const bf16_t* __restrict__ Bhi, const bf16_t* __restrict__ Blo,
             const float* __restrict__ bias,
             float* __restrict__ Cf, bf16_t* __restrict__ Cb,
             bf16_t* __restrict__ Cb2,
             int M, int Nc, int K)
{
  constexpr int NTILE = (PASSES == 3) ? 4 : 2;
  __shared__ __align__(16) bf16_t lds[NTILE * BM * BK];
  bf16_t* lAhi = lds;
  bf16_t* lBhi = lds + BM * BK;
  bf16_t* lAlo = (PASSES == 3) ? (lds + 2 * BM * BK) : nullptr;
  bf16_t* lBlo = (PASSES == 3) ? (lds + 3 * BM * BK) : nullptr;

  const int t = threadIdx.x;
  const int lane = t & 63;
  const int wave = t >> 6;
  const int wm = wave >> 1;
  const int wn = wave & 1;
  const int row0 = blockIdx.y * BM;
  const int col0 = blockIdx.x * BN;

  // staging: thread t loads 16B (8 bf16); 256 thr cover 64 rows x 32 cols
  const int srow = t >> 2;
  const int scol = (t & 3) * 8;
  const int loff = srow * BK + scol;

  // fragment addressing (16x16x32: A row = lane&15, k = (lane>>4)*8 + i)
  const int fr = lane & 15;
  const int kq = (lane >> 4) * 8;

  f32x4 acc[4][4] = {};

  for (int k0 = 0; k0 < K; k0 += BK) {
    const size_t ga = (size_t)(row0 + srow) * K + k0 + scol;
    const size_t gb = (size_t)(col0 + srow) * K + k0 + scol;
    gload16(Ahi + ga, lAhi + loff);
    gload16(Ahi + ga + (size_t)64 * K, lAhi + loff + 64 * BK);
    gload16(Bhi + gb, lBhi + loff);
    gload16(Bhi + gb + (size_t)64 * K, lBhi + loff + 64 * BK);
    if (PASSES == 3) {
      gload16(Alo + ga, lAlo + loff);
      gload16(Alo + ga + (size_t)64 * K, lAlo + loff + 64 * BK);
      gload16(Blo + gb, lBlo + loff);
      gload16(Blo + gb + (size_t)64 * K, lBlo + loff + 64 * BK);
    }
    __syncthreads();

    bf16x8 ah[4], bh[4], al[4], bl[4];
#pragma unroll
    for (int m = 0; m < 4; ++m)
      ah[m] = *(const bf16x8*)&lAhi[(wm * 64 + m * 16 + fr) * BK + kq];
#pragma unroll
    for (int n = 0; n < 4; ++n)
      bh[n] = *(const bf16x8*)&lBhi[(wn * 64 + n * 16 + fr) * BK + kq];
    if (PASSES == 3) {
#pragma unroll
      for (int m = 0; m < 4; ++m)
        al[m] = *(const bf16x8*)&lAlo[(wm * 64 + m * 16 + fr) * BK + kq];
#pragma unroll
      for (int n = 0; n < 4; ++n)
        bl[n] = *(const bf16x8*)&lBlo[(wn * 64 + n * 16 + fr) * BK + kq];
    }

#pragma unroll
    for (int m = 0; m < 4; ++m)
#pragma unroll
      for (int n = 0; n < 4; ++n) {
        acc[m][n] =
            __builtin_amdgcn_mfma_f32_16x16x32_bf16(ah[m], bh[n], acc[m][n], 0, 0, 0);
        if (PASSES == 3) {
          acc[m][n] =
              __builtin_amdgcn_mfma_f32_16x16x32_bf16(ah[m], bl[n], acc[m][n], 0, 0, 0);
          acc[m][n] =
              __builtin_amdgcn_mfma_f32_16x16x32_bf16(al[m], bh[n], acc[m][n], 0, 0, 0);
        }
      }
    __syncthreads();
  }

  // epilogue: C/D layout col = lane&15, row = (lane>>4)*4 + reg
#pragma unroll
  for (int m = 0; m < 4; ++m) {
#pragma unroll
    for (int n = 0; n < 4; ++n) {
      const int grow0 = row0 + wm * 64 + m * 16 + (lane >> 4) * 4;
      const int gcol = col0 + wn * 64 + n * 16 + (lane & 15);
      const float bv = bias ? bias[gcol] : 0.0f;
      if (EPI == EPI_BF16T) {
        // write transposed: Cb is [Nc][M]; 4 consecutive rows -> 8B store
        bf16x4 p;
#pragma unroll
        for (int r = 0; r < 4; ++r) p[r] = (bf16_t)(acc[m][n][r] + bv);
        *(bf16x4*)&Cb[(size_t)gcol * M + grow0] = p;
      } else {
#pragma unroll
        for (int r = 0; r < 4; ++r) {
          const float val = acc[m][n][r] + bv;
          const size_t idx = (size_t)(grow0 + r) * Nc + gcol;
          if (EPI == EPI_F32) {
            Cf[idx] = val;
          } else if (EPI == EPI_HILO) {
            const bf16_t h = (bf16_t)val;
            Cb[idx] = h;
            Cb2[idx] = (bf16_t)(val - (float)h);
          } else {  // EPI_BF16
            Cb[idx] = (bf16_t)val;
          }
        }
      }
    }
  }
}

// fp32 -> (hi, lo) bf16 split, vectorized x4. n4 = n/4.
__global__ __launch_bounds__(256)
void split_hilo(const float* __restrict__ x, bf16_t* __restrict__ hi,
                bf16_t* __restrict__ lo, int n4)
{
  const int i = blockIdx.x * 256 + threadIdx.x;
  if (i >= n4) return;
  const float4 v = ((const float4*)x)[i];
  const float vv[4] = {v.x, v.y, v.z, v.w};
  bf16x4 h, l;
#pragma unroll
  for (int j = 0; j < 4; ++j) {
    const bf16_t hh = (bf16_t)vv[j];
    h[j] = hh;
    l[j] = (bf16_t)(vv[j] - (float)hh);
  }
  ((bf16x4*)hi)[i] = h;
  ((bf16x4*)lo)[i] = l;
}

// in-place row softmax over [n] columns; also emits bf16 copy for the PV GEMM
__global__ __launch_bounds__(256)
void softmax_rows(float* __restrict__ S, bf16_t* __restrict__ P, int n)
{
  const int row = blockIdx.x;
  float* srow = S + (size_t)row * n;
  bf16_t* prow = P + (size_t)row * n;
  const int t = threadIdx.x;
  const int lane = t & 63;
  const int wave = t >> 6;
  __shared__ float red[8];

  float4 v[4];
  float mx = -3.4e38f;
#pragma unroll
  for (int i = 0; i < 4; ++i) {
    v[i] = *(const float4*)(srow + (size_t)(i * 256 + t) * 4);
    mx = fmaxf(mx, fmaxf(fmaxf(v[i].x, v[i].y), fmaxf(v[i].z, v[i].w)));
  }
#pragma unroll
  for (int off = 32; off > 0; off >>= 1) mx = fmaxf(mx, __shfl_xor(mx, off));
  if (lane == 0) red[wave] = mx;
  __syncthreads();
  mx = fmaxf(fmaxf(red[0], red[1]), fmaxf(red[2], red[3]));

  float e[16];
  float sum = 0.f;
#pragma unroll
  for (int i = 0; i < 4; ++i) {
    e[4 * i + 0] = __expf(v[i].x - mx);
    e[4 * i + 1] = __expf(v[i].y - mx);
    e[4 * i + 2] = __expf(v[i].z - mx);
    e[4 * i + 3] = __expf(v[i].w - mx);
    sum += e[4 * i + 0] + e[4 * i + 1] + e[4 * i + 2] + e[4 * i + 3];
  }
#pragma unroll
  for (int off = 32; off > 0; off >>= 1) sum += __shfl_xor(sum, off);
  if (lane == 0) red[4 + wave] = sum;
  __syncthreads();
  sum = red[4] + red[5] + red[6] + red[7];
  const float inv = 1.0f / sum;

#pragma unroll
  for (int i = 0; i < 4; ++i) {
    float4 w;
    w.x = e[4 * i + 0] * inv;
    w.y = e[4 * i + 1] * inv;
    w.z = e[4 * i + 2] * inv;
    w.w = e[4 * i + 3] * inv;
    *(float4*)(srow + (size_t)(i * 256 + t) * 4) = w;
    bf16x4 p;
    p[0] = (bf16_t)w.x;
    p[1] = (bf16_t)w.y;
    p[2] = (bf16_t)w.z;
    p[3] = (bf16_t)w.w;
    *(bf16x4*)(prow + (size_t)(i * 256 + t) * 4) = p;
  }
}

extern "C" void kernel_launch(void* const* d_in, const int* in_sizes, int n_in,
                              void* d_out, int out_size, void* d_ws, size_t ws_size,
                              hipStream_t stream) {
  const int N = N_SEQ, D = DMODEL;
  const float* q    = (const float*)d_in[0];
  const float* k    = (const float*)d_in[1];
  const float* v    = (const float*)d_in[2];
  const float* wq_w = (const float*)d_in[3];
  const float* wq_b = (const float*)d_in[4];
  const float* wk_w = (const float*)d_in[5];
  const float* wk_b = (const float*)d_in[6];
  const float* wv_w = (const float*)d_in[7];
  const float* wv_b = (const float*)d_in[8];
  const float* wo_w = (const float*)d_in[9];
  const float* wo_b = (const float*)d_in[10];

  float* x_out = (float*)d_out;                 // [N, D]
  float* attn  = x_out + (size_t)N * D;         // [N, N]

  // workspace layout (all 16B aligned; total ~100 MB)
  char* wsp = (char*)d_ws;
  auto alloc = [&](size_t bytes) { char* p = wsp; wsp += bytes; return p; };
  const size_t ND = (size_t)N * D, DD = (size_t)D * D, NN = (size_t)N * N;
  bf16_t* in_hi = (bf16_t*)alloc(ND * 2);
  bf16_t* in_lo = (bf16_t*)alloc(ND * 2);
  bf16_t* w_hi  = (bf16_t*)alloc(DD * 2);
  bf16_t* w_lo  = (bf16_t*)alloc(DD * 2);
  bf16_t* QPhi  = (bf16_t*)alloc(ND * 2);
  bf16_t* QPlo  = (bf16_t*)alloc(ND * 2);
  bf16_t* KPhi  = (bf16_t*)alloc(ND * 2);
  bf16_t* KPlo  = (bf16_t*)alloc(ND * 2);
  bf16_t* VPt   = (bf16_t*)alloc(ND * 2);       // [D][N] transposed
  bf16_t* Pb    = (bf16_t*)alloc(NN * 2);       // bf16 attention weights
  bf16_t* Xb    = (bf16_t*)alloc(ND * 2);       // attn @ vp, bf16

  const dim3 blk(256);
  const dim3 gproj(D / BN, N / BM);    // (8, 32)
  const dim3 gscore(N / BN, N / BM);   // (32, 32)

  auto split = [&](const float* x, bf16_t* hi, bf16_t* lo, size_t n) {
    const int n4 = (int)(n / 4);
    split_hilo<<<dim3((n4 + 255) / 256), blk, 0, stream>>>(x, hi, lo, n4);
  };

  // Q projection: qp = q @ wq^T + b  -> hi/lo bf16
  split(q, in_hi, in_lo, ND);
  split(wq_w, w_hi, w_lo, DD);
  gemm_bt<3, EPI_HILO><<<gproj, blk, 0, stream>>>(
      in_hi, in_lo, w_hi, w_lo, wq_b, nullptr, QPhi, QPlo, N, D, D);

  // K projection
  split(k, in_hi, in_lo, ND);
  split(wk_w, w_hi, w_lo, DD);
  gemm_bt<3, EPI_HILO><<<gproj, blk, 0, stream>>>(
      in_hi, in_lo, w_hi, w_lo, wk_b, nullptr, KPhi, KPlo, N, D, D);

  // V projection -> transposed bf16 [D][N]
  split(v, in_hi, in_lo, ND);
  split(wv_w, w_hi, w_lo, DD);
  gemm_bt<3, EPI_BF16T><<<gproj, blk, 0, stream>>>(
      in_hi, in_lo, w_hi, w_lo, wv_b, nullptr, VPt, nullptr, N, D, D);

  // scores = qp @ kp^T  (fp32, straight into d_out attention region)
  gemm_bt<3, EPI_F32><<<gscore, blk, 0, stream>>>(
      QPhi, QPlo, KPhi, KPlo, nullptr, attn, nullptr, nullptr, N, N, D);

  // softmax rows in-place + bf16 copy
  softmax_rows<<<dim3(N), blk, 0, stream>>>(attn, Pb, N);

  // X = P @ VP   (P [N,N] bf16, VPt [D][N] as B^T)
  gemm_bt<1, EPI_BF16><<<gproj, blk, 0, stream>>>(
      Pb, nullptr, VPt, nullptr, nullptr, nullptr, Xb, nullptr, N, D, N);

  // out = X @ wo^T + b  (fp32 into d_out)
  split(wo_w, w_hi, w_lo, DD);
  gemm_bt<1, EPI_F32><<<gproj, blk, 0, stream>>>(
      Xb, nullptr, w_hi, nullptr, wo_b, x_out, nullptr, nullptr, N, D, D);
}

// Round 2
// 402.133 us; speedup vs baseline: 1.0686x; 1.0686x over previous
//
#include <hip/hip_runtime.h>
#include <cstdint>

// Problem constants (fixed by the reference)
#define N_SEQ 4096
#define DMODEL 1024

#define BM 128
#define BN 128
#define BK 32

typedef __bf16 bf16_t;
typedef bf16_t bf16x8 __attribute__((ext_vector_type(8)));
typedef bf16_t bf16x4 __attribute__((ext_vector_type(4)));
typedef float f32x4 __attribute__((ext_vector_type(4)));

typedef __attribute__((address_space(1))) void* as1ptr;
typedef __attribute__((address_space(3))) void* as3ptr;

__device__ __forceinline__ void gload16(const bf16_t* g, bf16_t* l) {
  __builtin_amdgcn_global_load_lds((as1ptr)(uintptr_t)g, (as3ptr)(uintptr_t)l,
                                   16, 0, 0);
}

enum { EPI_F32 = 0, EPI_HILO = 1, EPI_BF16T = 2, EPI_BF16 = 3 };

// ======================= m97-structure 128x128 GEMM =======================
// C[M,Nc] = (Ahi+Alo)[M,K] @ (Bhi+Blo)[Nc,K]^T  (+ bias[col])
template <int PASSES, int EPI>
__global__ __launch_bounds__(256)
void gemm_bt(const bf16_t* __restrict__ Ahi, const bf16_t* __restrict__ Alo,
             const bf16_t* __restrict__ Bhi, const bf16_t* __restrict__ Blo,
             const float* __restrict__ bias,
             float* __restrict__ Cf, bf16_t* __restrict__ Cb,
             bf16_t* __restrict__ Cb2,
             int M, int Nc, int K)
{
  constexpr int NTILE = (PASSES == 3) ? 4 : 2;
  __shared__ __align__(16) bf16_t lds[NTILE * BM * BK];
  bf16_t* lAhi = lds;
  bf16_t* lBhi = lds + BM * BK;
  bf16_t* lAlo = (PASSES == 3) ? (lds + 2 * BM * BK) : nullptr;
  bf16_t* lBlo = (PASSES == 3) ? (lds + 3 * BM * BK) : nullptr;

  const int t = threadIdx.x;
  const int lane = t & 63;
  const int wave = t >> 6;
  const int wm = wave >> 1;
  const int wn = wave & 1;
  const int row0 = blockIdx.y * BM;
  const int col0 = blockIdx.x * BN;

  const int srow = t >> 2;
  const int scol = (t & 3) * 8;
  const int loff = srow * BK + scol;

  const int fr = lane & 15;
  const int kq = (lane >> 4) * 8;

  f32x4 acc[4][4] = {};

  for (int k0 = 0; k0 < K; k0 += BK) {
    const size_t ga = (size_t)(row0 + srow) * K + k0 + scol;
    const size_t gb = (size_t)(col0 + srow) * K + k0 + scol;
    gload16(Ahi + ga, lAhi + loff);
    gload16(Ahi + ga + (size_t)64 * K, lAhi + loff + 64 * BK);
    gload16(Bhi + gb, lBhi + loff);
    gload16(Bhi + gb + (size_t)64 * K, lBhi + loff + 64 * BK);
    if (PASSES == 3) {
      gload16(Alo + ga, lAlo + loff);
      gload16(Alo + ga + (size_t)64 * K, lAlo + loff + 64 * BK);
      gload16(Blo + gb, lBlo + loff);
      gload16(Blo + gb + (size_t)64 * K, lBlo + loff + 64 * BK);
    }
    __syncthreads();

    bf16x8 ah[4], bh[4], al[4], bl[4];
#pragma unroll
    for (int m = 0; m < 4; ++m)
      ah[m] = *(const bf16x8*)&lAhi[(wm * 64 + m * 16 + fr) * BK + kq];
#pragma unroll
    for (int n = 0; n < 4; ++n)
      bh[n] = *(const bf16x8*)&lBhi[(wn * 64 + n * 16 + fr) * BK + kq];
    if (PASSES == 3) {
#pragma unroll
      for (int m = 0; m < 4; ++m)
        al[m] = *(const bf16x8*)&lAlo[(wm * 64 + m * 16 + fr) * BK + kq];
#pragma unroll
      for (int n = 0; n < 4; ++n)
        bl[n] = *(const bf16x8*)&lBlo[(wn * 64 + n * 16 + fr) * BK + kq];
    }

#pragma unroll
    for (int m = 0; m < 4; ++m)
#pragma unroll
      for (int n = 0; n < 4; ++n) {
        acc[m][n] =
            __builtin_amdgcn_mfma_f32_16x16x32_bf16(ah[m], bh[n], acc[m][n], 0, 0, 0);
        if (PASSES == 3) {
          acc[m][n] =
              __builtin_amdgcn_mfma_f32_16x16x32_bf16(ah[m], bl[n], acc[m][n], 0, 0, 0);
          acc[m][n] =
              __builtin_amdgcn_mfma_f32_16x16x32_bf16(al[m], bh[n], acc[m][n], 0, 0, 0);
        }
      }
    __syncthreads();
  }

#pragma unroll
  for (int m = 0; m < 4; ++m) {
#pragma unroll
    for (int n = 0; n < 4; ++n) {
      const int grow0 = row0 + wm * 64 + m * 16 + (lane >> 4) * 4;
      const int gcol = col0 + wn * 64 + n * 16 + (lane & 15);
      const float bv = bias ? bias[gcol] : 0.0f;
      if (EPI == EPI_BF16T) {
        bf16x4 p;
#pragma unroll
        for (int r = 0; r < 4; ++r) p[r] = (bf16_t)(acc[m][n][r] + bv);
        *(bf16x4*)&Cb[(size_t)gcol * M + grow0] = p;
      } else {
#pragma unroll
        for (int r = 0; r < 4; ++r) {
          const float val = acc[m][n][r] + bv;
          const size_t idx = (size_t)(grow0 + r) * Nc + gcol;
          if (EPI == EPI_F32) {
            Cf[idx] = val;
          } else if (EPI == EPI_HILO) {
            const bf16_t h = (bf16_t)val;
            Cb[idx] = h;
            Cb2[idx] = (bf16_t)(val - (float)h);
          } else {
            Cb[idx] = (bf16_t)val;
          }
        }
      }
    }
  }
}

// ======================= 8-phase 256x256 scores GEMM =======================
// scores = (Qhi+Qlo) @ (Khi+Klo)^T realized as single-pass bf16 GEMM with
// logical K = 3*1024: ktile 0-15 -> Ahi*Bhi, 16-31 -> Ahi*Blo, 32-47 -> Alo*Bhi.
// M = Nc = 4096, physical row stride 1024. BM=BN=256, BK=64, 512 thr (8 waves).
#define TILE_ELEMS 16384   // 256 rows x 64 cols
#define UNIT_ELEMS 4096    // 64 rows x 64 cols
#define NT_SC 48

template <int V> struct ic { static constexpr int value = V; };

#define SBAR() asm volatile("s_barrier" ::: "memory")
#define WAITLGKM()                                         \
  do {                                                     \
    asm volatile("s_waitcnt lgkmcnt(0)" ::: "memory");     \
    __builtin_amdgcn_sched_barrier(0);                     \
  } while (0)

template <int MH>
__device__ __forceinline__ void load_A8(const bf16_t* Ab, int wm, int fr,
                                        int kq, int sw, bf16x8 (&af)[4][2]) {
#pragma unroll
  for (int m = 0; m < 4; ++m) {
    const int row = wm * 128 + (MH * 4 + m) * 16 + fr;
#pragma unroll
    for (int ks = 0; ks < 2; ++ks)
      af[m][ks] = *(const bf16x8*)&Ab[row * 64 + ((ks * 32 + kq) ^ sw)];
  }
}

template <int NH>
__device__ __forceinline__ void load_B8(const bf16_t* Bb, int wn, int fr,
                                        int kq, int sw, bf16x8 (&bfr)[2][2]) {
#pragma unroll
  for (int n = 0; n < 2; ++n) {
    const int row = wn * 64 + (NH * 2 + n) * 16 + fr;
#pragma unroll
    for (int ks = 0; ks < 2; ++ks)
      bfr[n][ks] = *(const bf16x8*)&Bb[row * 64 + ((ks * 32 + kq) ^ sw)];
  }
}

template <int MH, int NH>
__device__ __forceinline__ void mfma16(const bf16x8 (&af)[4][2],
                                       const bf16x8 (&bfr)[2][2],
                                       f32x4 (&acc)[8][4]) {
#pragma unroll
  for (int m = 0; m < 4; ++m)
#pragma unroll
    for (int n = 0; n < 2; ++n)
#pragma unroll
      for (int ks = 0; ks < 2; ++ks)
        acc[MH * 4 + m][NH * 2 + n] = __builtin_amdgcn_mfma_f32_16x16x32_bf16(
            af[m][ks], bfr[n][ks], acc[MH * 4 + m][NH * 2 + n], 0, 0, 0);
}

__global__ __launch_bounds__(512, 2)
void gemm8_scores(const bf16_t* __restrict__ Ahi, const bf16_t* __restrict__ Alo,
                  const bf16_t* __restrict__ Bhi, const bf16_t* __restrict__ Blo,
                  float* __restrict__ C)
{
  __shared__ __align__(16) bf16_t sm[2 * 2 * TILE_ELEMS];  // 128 KiB

  const int t = threadIdx.x;
  const int lane = t & 63;
  const int wave = t >> 6;
  const int wm = wave >> 2;      // 0..1
  const int wn = wave & 3;       // 0..3
  const int brow = blockIdx.y * 256;
  const int bcol = blockIdx.x * 256;

  // staging: thread t covers linear dest elems [t*8, t*8+8) within a unit.
  // full-XOR swizzle (involution): element col c stored at lin = c ^ ((row&7)<<3)
  const int srow = t >> 3;                               // 0..63
  const int scol = 8 * ((t & 7) ^ ((t >> 3) & 7));       // pre-swizzled src col
  const int sdst = t * 8;

  // fragment addressing
  const int fr = lane & 15;
  const int kq = (lane >> 4) * 8;
  const int sw = (fr & 7) << 3;                          // read-side swizzle

  auto stageA = [&](int buf, int u, int kt) {
    const int seg = kt >> 4;                 // 0,1 -> hi ; 2 -> lo
    const bf16_t* src = (seg == 2) ? Alo : Ahi;
    const int kk = (kt & 15) << 6;
    gload16(src + (size_t)(brow + u * 64 + srow) * DMODEL + kk + scol,
            &sm[(buf * 2 + 0) * TILE_ELEMS + u * UNIT_ELEMS + sdst]);
  };
  auto stageB = [&](int buf, int u, int kt) {
    const int seg = kt >> 4;                 // 0,2 -> hi ; 1 -> lo
    const bf16_t* src = (seg == 1) ? Blo : Bhi;
    const int kk = (kt & 15) << 6;
    gload16(src + (size_t)(bcol + u * 64 + srow) * DMODEL + kk + scol,
            &sm[(buf * 2 + 1) * TILE_ELEMS + u * UNIT_ELEMS + sdst]);
  };

  f32x4 acc[8][4] = {};
  bf16x8 af[4][2];
  bf16x8 bfr[2][2];

  // ---- prologue: K-tile 0 fully into buf0; K-tile 1's A-U0,A-U2 into buf1.
#pragma unroll
  for (int u = 0; u < 4; ++u) stageA(0, u, 0);
#pragma unroll
  for (int u = 0; u < 4; ++u) stageB(0, u, 0);
  stageA(1, 0, 1);
  stageA(1, 2, 1);
  asm volatile("s_waitcnt vmcnt(2)" ::: "memory");  // K0's 8 landed
  SBAR();

  auto tile = [&](auto Pc, int kt) {
    constexpr int p = decltype(Pc)::value;
    constexpr int q = p ^ 1;
    const bool n1 = (kt + 1 < NT_SC);
    const bool n2 = (kt + 2 < NT_SC);
    const bf16_t* Ab = &sm[(p * 2 + 0) * TILE_ELEMS];
    const bf16_t* Bb = &sm[(p * 2 + 1) * TILE_ELEMS];

    // ---- Phase 1: (MH0,NH0); stage t+1: A-U1,A-U3,B-V0,B-V1 -> buf q
    load_A8<0>(Ab, wm, fr, kq, sw, af);
    load_B8<0>(Bb, wn, fr, kq, sw, bfr);
    if (n1) { stageA(q, 1, kt + 1); stageA(q, 3, kt + 1);
              stageB(q, 0, kt + 1); stageB(q, 1, kt + 1); }
    SBAR();
    WAITLGKM();
    __builtin_amdgcn_s_setprio(1);
    mfma16<0, 0>(af, bfr, acc);
    __builtin_amdgcn_s_setprio(0);
    __builtin_amdgcn_sched_barrier(0);
    SBAR();

    // ---- Phase 2: (MH0,NH1); stage t+1: B-V2,B-V3
    load_B8<1>(Bb, wn, fr, kq, sw, bfr);
    if (n1) { stageB(q, 2, kt + 1); stageB(q, 3, kt + 1); }
    SBAR();
    WAITLGKM();
    __builtin_amdgcn_s_setprio(1);
    mfma16<0, 1>(af, bfr, acc);
    __builtin_amdgcn_s_setprio(0);
    __builtin_amdgcn_sched_barrier(0);
    SBAR();

    // ---- Phase 3: (MH1,NH0); no staging
    load_A8<1>(Ab, wm, fr, kq, sw, af);
    load_B8<0>(Bb, wn, fr, kq, sw, bfr);
    SBAR();
    WAITLGKM();
    __builtin_amdgcn_s_setprio(1);
    mfma16<1, 0>(af, bfr, acc);
    __builtin_amdgcn_s_setprio(0);
    __builtin_amdgcn_sched_barrier(0);
    SBAR();

    // ---- Phase 4: (MH1,NH1); stage t+2: A-U0,A-U2 -> buf p (dead since Ph2)
    load_B8<1>(Bb, wn, fr, kq, sw, bfr);
    if (n2) { stageA(p, 0, kt + 2); stageA(p, 2, kt + 2); }
    SBAR();
    WAITLGKM();
    __builtin_amdgcn_s_setprio(1);
    mfma16<1, 1>(af, bfr, acc);
    __builtin_amdgcn_s_setprio(0);
    __builtin_amdgcn_sched_barrier(0);
    if (n2)      asm volatile("s_waitcnt vmcnt(2)" ::: "memory");
    else if (n1) asm volatile("s_waitcnt vmcnt(0)" ::: "memory");
    SBAR();
  };

  for (int kt = 0; kt < NT_SC; kt += 2) {
    tile(ic<0>{}, kt);
    tile(ic<1>{}, kt + 1);
  }

  // ---- epilogue: C/D layout col = lane&15, row = (lane>>4)*4 + reg
#pragma unroll
  for (int mf = 0; mf < 8; ++mf) {
#pragma unroll
    for (int nf = 0; nf < 4; ++nf) {
      const int r0 = brow + wm * 128 + mf * 16 + (lane >> 4) * 4;
      const int c  = bcol + wn * 64 + nf * 16 + (lane & 15);
#pragma unroll
      for (int r = 0; r < 4; ++r)
        C[(size_t)(r0 + r) * N_SEQ + c] = acc[mf][nf][r];
    }
  }
}

// ======================= helpers =======================
__global__ __launch_bounds__(256)
void split_hilo(const float* __restrict__ x, bf16_t* __restrict__ hi,
                bf16_t* __restrict__ lo, int n4)
{
  const int i = blockIdx.x * 256 + threadIdx.x;
  if (i >= n4) return;
  const float4 v = ((const float4*)x)[i];
  const float vv[4] = {v.x, v.y, v.z, v.w};
  bf16x4 h, l;
#pragma unroll
  for (int j = 0; j < 4; ++j) {
    const bf16_t hh = (bf16_t)vv[j];
    h[j] = hh;
    l[j] = (bf16_t)(vv[j] - (float)hh);
  }
  ((bf16x4*)hi)[i] = h;
  ((bf16x4*)lo)[i] = l;
}

__global__ __launch_bounds__(256)
void softmax_rows(float* __restrict__ S, bf16_t* __restrict__ P, int n)
{
  const int row = blockIdx.x;
  float* srow = S + (size_t)row * n;
  bf16_t* prow = P + (size_t)row * n;
  const int t = threadIdx.x;
  const int lane = t & 63;
  const int wave = t >> 6;
  __shared__ float red[8];

  float4 v[4];
  float mx = -3.4e38f;
#pragma unroll
  for (int i = 0; i < 4; ++i) {
    v[i] = *(const float4*)(srow + (size_t)(i * 256 + t) * 4);
    mx = fmaxf(mx, fmaxf(fmaxf(v[i].x, v[i].y), fmaxf(v[i].z, v[i].w)));
  }
#pragma unroll
  for (int off = 32; off > 0; off >>= 1) mx = fmaxf(mx, __shfl_xor(mx, off));
  if (lane == 0) red[wave] = mx;
  __syncthreads();
  mx = fmaxf(fmaxf(red[0], red[1]), fmaxf(red[2], red[3]));

  float e[16];
  float sum = 0.f;
#pragma unroll
  for (int i = 0; i < 4; ++i) {
    e[4 * i + 0] = __expf(v[i].x - mx);
    e[4 * i + 1] = __expf(v[i].y - mx);
    e[4 * i + 2] = __expf(v[i].z - mx);
    e[4 * i + 3] = __expf(v[i].w - mx);
    sum += e[4 * i + 0] + e[4 * i + 1] + e[4 * i + 2] + e[4 * i + 3];
  }
#pragma unroll
  for (int off = 32; off > 0; off >>= 1) sum += __shfl_xor(sum, off);
  if (lane == 0) red[4 + wave] = sum;
  __syncthreads();
  sum = red[4] + red[5] + red[6] + red[7];
  const float inv = 1.0f / sum;

#pragma unroll
  for (int i = 0; i < 4; ++i) {
    float4 w;
    w.x = e[4 * i + 0] * inv;
    w.y = e[4 * i + 1] * inv;
    w.z = e[4 * i + 2] * inv;
    w.w = e[4 * i + 3] * inv;
    *(float4*)(srow + (size_t)(i * 256 + t) * 4) = w;
    bf16x4 p;
    p[0] = (bf16_t)w.x;
    p[1] = (bf16_t)w.y;
    p[2] = (bf16_t)w.z;
    p[3] = (bf16_t)w.w;
    *(bf16x4*)(prow + (size_t)(i * 256 + t) * 4) = p;
  }
}

extern "C" void kernel_launch(void* const* d_in, const int* in_sizes, int n_in,
                              void* d_out, int out_size, void* d_ws, size_t ws_size,
                              hipStream_t stream) {
  const int N = N_SEQ, D = DMODEL;
  const float* q    = (const float*)d_in[0];
  const float* k    = (const float*)d_in[1];
  const float* v    = (const float*)d_in[2];
  const float* wq_w = (const float*)d_in[3];
  const float* wq_b = (const float*)d_in[4];
  const float* wk_w = (const float*)d_in[5];
  const float* wk_b = (const float*)d_in[6];
  const float* wv_w = (const float*)d_in[7];
  const float* wv_b = (const float*)d_in[8];
  const float* wo_w = (const float*)d_in[9];
  const float* wo_b = (const float*)d_in[10];

  float* x_out = (float*)d_out;                 // [N, D]
  float* attn  = x_out + (size_t)N * D;         // [N, N]

  char* wsp = (char*)d_ws;
  auto alloc = [&](size_t bytes) { char* p = wsp; wsp += bytes; return p; };
  const size_t ND = (size_t)N * D, DD = (size_t)D * D, NN = (size_t)N * N;
  bf16_t* in_hi = (bf16_t*)alloc(ND * 2);
  bf16_t* in_lo = (bf16_t*)alloc(ND * 2);
  bf16_t* w_hi  = (bf16_t*)alloc(DD * 2);
  bf16_t* w_lo  = (bf16_t*)alloc(DD * 2);
  bf16_t* QPhi  = (bf16_t*)alloc(ND * 2);
  bf16_t* QPlo  = (bf16_t*)alloc(ND * 2);
  bf16_t* KPhi  = (bf16_t*)alloc(ND * 2);
  bf16_t* KPlo  = (bf16_t*)alloc(ND * 2);
  bf16_t* VPt   = (bf16_t*)alloc(ND * 2);       // [D][N] transposed
  bf16_t* Pb    = (bf16_t*)alloc(NN * 2);       // bf16 attention weights
  bf16_t* Xb    = (bf16_t*)alloc(ND * 2);       // attn @ vp, bf16

  const dim3 blk(256);
  const dim3 gproj(D / BN, N / BM);    // (8, 32)
  const dim3 gsc(N / 256, N / 256);    // (16, 16)

  auto split = [&](const float* x, bf16_t* hi, bf16_t* lo, size_t n) {
    const int n4 = (int)(n / 4);
    split_hilo<<<dim3((n4 + 255) / 256), blk, 0, stream>>>(x, hi, lo, n4);
  };

  // Q projection (3-pass hi/lo precision)
  split(q, in_hi, in_lo, ND);
  split(wq_w, w_hi, w_lo, DD);
  gemm_bt<3, EPI_HILO><<<gproj, blk, 0, stream>>>(
      in_hi, in_lo, w_hi, w_lo, wq_b, nullptr, QPhi, QPlo, N, D, D);

  // K projection (3-pass)
  split(k, in_hi, in_lo, ND);
  split(wk_w, w_hi, w_lo, DD);
  gemm_bt<3, EPI_HILO><<<gproj, blk, 0, stream>>>(
      in_hi, in_lo, w_hi, w_lo, wk_b, nullptr, KPhi, KPlo, N, D, D);

  // V projection (1-pass suffices: errors unamplified through softmax-avg)
  split(v, in_hi, in_lo, ND);
  split(wv_w, w_hi, w_lo, DD);
  gemm_bt<1, EPI_BF16T><<<gproj, blk, 0, stream>>>(
      in_hi, nullptr, w_hi, nullptr, wv_b, nullptr, VPt, nullptr, N, D, D);

  // scores = qp @ kp^T  (8-phase 256^2, logical K=3072, fp32 into d_out)
  gemm8_scores<<<gsc, dim3(512), 0, stream>>>(QPhi, QPlo, KPhi, KPlo, attn);

  // softmax rows in-place + bf16 copy
  softmax_rows<<<dim3(N), blk, 0, stream>>>(attn, Pb, N);

  // X = P @ VP
  gemm_bt<1, EPI_BF16><<<gproj, blk, 0, stream>>>(
      Pb, nullptr, VPt, nullptr, nullptr, nullptr, Xb, nullptr, N, D, N);

  // out = X @ wo^T + b
  split(wo_w, w_hi, w_lo, DD);
  gemm_bt<1, EPI_F32><<<gproj, blk, 0, stream>>>(
      Xb, nullptr, w_hi, nullptr, wo_b, x_out, nullptr, nullptr, N, D, D);
}

// Round 3
// 387.913 us; speedup vs baseline: 1.1077x; 1.0367x over previous
//
#include <hip/hip_runtime.h>
#include <cstdint>

// Problem constants (fixed by the reference)
#define N_SEQ 4096
#define DMODEL 1024

#define BM 128
#define BN 128
#define BK 32

typedef __bf16 bf16_t;
typedef bf16_t bf16x8 __attribute__((ext_vector_type(8)));
typedef bf16_t bf16x4 __attribute__((ext_vector_type(4)));
typedef float f32x4 __attribute__((ext_vector_type(4)));

typedef __attribute__((address_space(1))) void* as1ptr;
typedef __attribute__((address_space(3))) void* as3ptr;

__device__ __forceinline__ void gload16(const bf16_t* g, bf16_t* l) {
  __builtin_amdgcn_global_load_lds((as1ptr)(uintptr_t)g, (as3ptr)(uintptr_t)l,
                                   16, 0, 0);
}

enum { EPI_F32 = 0, EPI_HILO = 1, EPI_BF16T = 2, EPI_BF16 = 3 };

// ======================= m97-structure 128x128 GEMM =======================
template <int PASSES, int EPI>
__global__ __launch_bounds__(256)
void gemm_bt(const bf16_t* __restrict__ Ahi, const bf16_t* __restrict__ Alo,
             const bf16_t* __restrict__ Bhi, const bf16_t* __restrict__ Blo,
             const float* __restrict__ bias,
             float* __restrict__ Cf, bf16_t* __restrict__ Cb,
             bf16_t* __restrict__ Cb2,
             int M, int Nc, int K)
{
  constexpr int NTILE = (PASSES == 3) ? 4 : 2;
  __shared__ __align__(16) bf16_t lds[NTILE * BM * BK];
  bf16_t* lAhi = lds;
  bf16_t* lBhi = lds + BM * BK;
  bf16_t* lAlo = (PASSES == 3) ? (lds + 2 * BM * BK) : nullptr;
  bf16_t* lBlo = (PASSES == 3) ? (lds + 3 * BM * BK) : nullptr;

  const int t = threadIdx.x;
  const int lane = t & 63;
  const int wave = t >> 6;
  const int wm = wave >> 1;
  const int wn = wave & 1;
  const int row0 = blockIdx.y * BM;
  const int col0 = blockIdx.x * BN;

  const int srow = t >> 2;
  const int scol = (t & 3) * 8;
  const int loff = srow * BK + scol;

  const int fr = lane & 15;
  const int kq = (lane >> 4) * 8;

  f32x4 acc[4][4] = {};

  for (int k0 = 0; k0 < K; k0 += BK) {
    const size_t ga = (size_t)(row0 + srow) * K + k0 + scol;
    const size_t gb = (size_t)(col0 + srow) * K + k0 + scol;
    gload16(Ahi + ga, lAhi + loff);
    gload16(Ahi + ga + (size_t)64 * K, lAhi + loff + 64 * BK);
    gload16(Bhi + gb, lBhi + loff);
    gload16(Bhi + gb + (size_t)64 * K, lBhi + loff + 64 * BK);
    if (PASSES == 3) {
      gload16(Alo + ga, lAlo + loff);
      gload16(Alo + ga + (size_t)64 * K, lAlo + loff + 64 * BK);
      gload16(Blo + gb, lBlo + loff);
      gload16(Blo + gb + (size_t)64 * K, lBlo + loff + 64 * BK);
    }
    __syncthreads();

    bf16x8 ah[4], bh[4], al[4], bl[4];
#pragma unroll
    for (int m = 0; m < 4; ++m)
      ah[m] = *(const bf16x8*)&lAhi[(wm * 64 + m * 16 + fr) * BK + kq];
#pragma unroll
    for (int n = 0; n < 4; ++n)
      bh[n] = *(const bf16x8*)&lBhi[(wn * 64 + n * 16 + fr) * BK + kq];
    if (PASSES == 3) {
#pragma unroll
      for (int m = 0; m < 4; ++m)
        al[m] = *(const bf16x8*)&lAlo[(wm * 64 + m * 16 + fr) * BK + kq];
#pragma unroll
      for (int n = 0; n < 4; ++n)
        bl[n] = *(const bf16x8*)&lBlo[(wn * 64 + n * 16 + fr) * BK + kq];
    }

#pragma unroll
    for (int m = 0; m < 4; ++m)
#pragma unroll
      for (int n = 0; n < 4; ++n) {
        acc[m][n] =
            __builtin_amdgcn_mfma_f32_16x16x32_bf16(ah[m], bh[n], acc[m][n], 0, 0, 0);
        if (PASSES == 3) {
          acc[m][n] =
              __builtin_amdgcn_mfma_f32_16x16x32_bf16(ah[m], bl[n], acc[m][n], 0, 0, 0);
          acc[m][n] =
              __builtin_amdgcn_mfma_f32_16x16x32_bf16(al[m], bh[n], acc[m][n], 0, 0, 0);
        }
      }
    __syncthreads();
  }

#pragma unroll
  for (int m = 0; m < 4; ++m) {
#pragma unroll
    for (int n = 0; n < 4; ++n) {
      const int grow0 = row0 + wm * 64 + m * 16 + (lane >> 4) * 4;
      const int gcol = col0 + wn * 64 + n * 16 + (lane & 15);
      const float bv = bias ? bias[gcol] : 0.0f;
      if (EPI == EPI_BF16T) {
        bf16x4 p;
#pragma unroll
        for (int r = 0; r < 4; ++r) p[r] = (bf16_t)(acc[m][n][r] + bv);
        *(bf16x4*)&Cb[(size_t)gcol * M + grow0] = p;
      } else {
#pragma unroll
        for (int r = 0; r < 4; ++r) {
          const float val = acc[m][n][r] + bv;
          const size_t idx = (size_t)(grow0 + r) * Nc + gcol;
          if (EPI == EPI_F32) {
            Cf[idx] = val;
          } else if (EPI == EPI_HILO) {
            const bf16_t h = (bf16_t)val;
            Cb[idx] = h;
            Cb2[idx] = (bf16_t)(val - (float)h);
          } else {
            Cb[idx] = (bf16_t)val;
          }
        }
      }
    }
  }
}

// ======================= 8-phase 256x256 scores GEMM (v3) =======================
// scores = (Qhi+Qlo)(Khi+Klo)^T as single-pass bf16 with logical K = 3*1024.
// v3: B-fragments register-cached (24 ds_read_b128/wave/tile instead of 32);
// deep staging cadence 2 loads/phase, single vmcnt(6)/tile (4-7 phase depth).
#define TILE_ELEMS 16384   // 256 rows x 64 cols
#define UNIT_ELEMS 4096    // 64 rows x 64 cols
#define NT_SC 48

template <int V> struct ic { static constexpr int value = V; };

#define SBAR() asm volatile("s_barrier" ::: "memory")
#define WAITLGKM()                                         \
  do {                                                     \
    asm volatile("s_waitcnt lgkmcnt(0)" ::: "memory");     \
    __builtin_amdgcn_sched_barrier(0);                     \
  } while (0)

template <int MH>
__device__ __forceinline__ void load_A8(const bf16_t* Ab, int wm, int fr,
                                        int kq, int sw, bf16x8 (&af)[4][2]) {
#pragma unroll
  for (int m = 0; m < 4; ++m) {
    const int row = wm * 128 + (MH * 4 + m) * 16 + fr;
#pragma unroll
    for (int ks = 0; ks < 2; ++ks)
      af[m][ks] = *(const bf16x8*)&Ab[row * 64 + ((ks * 32 + kq) ^ sw)];
  }
}

template <int NH>
__device__ __forceinline__ void load_B4(const bf16_t* Bb, int wn, int fr,
                                        int kq, int sw, bf16x8 (&bfr)[2][2]) {
#pragma unroll
  for (int n = 0; n < 2; ++n) {
    const int row = wn * 64 + (NH * 2 + n) * 16 + fr;
#pragma unroll
    for (int ks = 0; ks < 2; ++ks)
      bfr[n][ks] = *(const bf16x8*)&Bb[row * 64 + ((ks * 32 + kq) ^ sw)];
  }
}

template <int MH, int NH>
__device__ __forceinline__ void mfma16(const bf16x8 (&af)[4][2],
                                       const bf16x8 (&bfr)[2][2],
                                       f32x4 (&acc)[8][4]) {
#pragma unroll
  for (int m = 0; m < 4; ++m)
#pragma unroll
    for (int n = 0; n < 2; ++n)
#pragma unroll
      for (int ks = 0; ks < 2; ++ks)
        acc[MH * 4 + m][NH * 2 + n] = __builtin_amdgcn_mfma_f32_16x16x32_bf16(
            af[m][ks], bfr[n][ks], acc[MH * 4 + m][NH * 2 + n], 0, 0, 0);
}

__global__ __launch_bounds__(512, 2)
void gemm8_scores(const bf16_t* __restrict__ Ahi, const bf16_t* __restrict__ Alo,
                  const bf16_t* __restrict__ Bhi, const bf16_t* __restrict__ Blo,
                  float* __restrict__ C)
{
  __shared__ __align__(16) bf16_t sm[2 * 2 * TILE_ELEMS];  // 128 KiB

  const int t = threadIdx.x;
  const int lane = t & 63;
  const int wave = t >> 6;
  const int wm = wave >> 2;      // 0..1
  const int wn = wave & 3;       // 0..3
  const int brow = blockIdx.y * 256;
  const int bcol = blockIdx.x * 256;

  // staging: thread t covers linear dest elems [t*8, t*8+8) within a unit;
  // pre-swizzled source column (involution with the read-side XOR).
  const int srow = t >> 3;                               // 0..63
  const int scol = 8 * ((t & 7) ^ ((t >> 3) & 7));       // pre-swizzled src col
  const int sdst = t * 8;

  const int fr = lane & 15;
  const int kq = (lane >> 4) * 8;
  const int sw = (fr & 7) << 3;                          // read-side swizzle

  auto stageA = [&](int buf, int u, int kt) {
    const int seg = kt >> 4;                 // 0,1 -> hi ; 2 -> lo
    const bf16_t* src = (seg == 2) ? Alo : Ahi;
    const int kk = (kt & 15) << 6;
    gload16(src + (size_t)(brow + u * 64 + srow) * DMODEL + kk + scol,
            &sm[(buf * 2 + 0) * TILE_ELEMS + u * UNIT_ELEMS + sdst]);
  };
  auto stageB = [&](int buf, int u, int kt) {
    const int seg = kt >> 4;                 // 0,2 -> hi ; 1 -> lo
    const bf16_t* src = (seg == 1) ? Blo : Bhi;
    const int kk = (kt & 15) << 6;
    gload16(src + (size_t)(bcol + u * 64 + srow) * DMODEL + kk + scol,
            &sm[(buf * 2 + 1) * TILE_ELEMS + u * UNIT_ELEMS + sdst]);
  };

  f32x4 acc[8][4] = {};
  bf16x8 af[4][2];
  bf16x8 b0[2][2], b1[2][2];   // NH0 / NH1 fragments, cached across phases

  // ---- prologue: tile0 all 8 units; tile1's Ua, V01, Ub (6 loads).
#pragma unroll
  for (int u = 0; u < 4; ++u) stageA(0, u, 0);
#pragma unroll
  for (int u = 0; u < 4; ++u) stageB(0, u, 0);
  stageA(1, 0, 1); stageA(1, 2, 1);   // Ua(1)
  stageB(1, 0, 1); stageB(1, 1, 1);   // V01(1)
  stageA(1, 1, 1); stageA(1, 3, 1);   // Ub(1)
  asm volatile("s_waitcnt vmcnt(6)" ::: "memory");  // tile0's 8 landed
  SBAR();

  auto tile = [&](auto Pc, int kt) {
    constexpr int p = decltype(Pc)::value;
    constexpr int q = p ^ 1;
    const bool n1 = (kt + 1 < NT_SC);
    const bool n2 = (kt + 2 < NT_SC);
    const bf16_t* Ab = &sm[(p * 2 + 0) * TILE_ELEMS];
    const bf16_t* Bb = &sm[(p * 2 + 1) * TILE_ELEMS];

    // ---- Phase 1: MH0 x NH0.  reads: A-MH0 (8) + B-NH0 (4).  stage: V23(t+1)
    load_A8<0>(Ab, wm, fr, kq, sw, af);
    load_B4<0>(Bb, wn, fr, kq, sw, b0);
    if (n1) { stageB(q, 2, kt + 1); stageB(q, 3, kt + 1); }
    SBAR();
    WAITLGKM();
    __builtin_amdgcn_s_setprio(1);
    mfma16<0, 0>(af, b0, acc);
    __builtin_amdgcn_s_setprio(0);
    __builtin_amdgcn_sched_barrier(0);
    SBAR();

    // ---- Phase 2: MH0 x NH1.  reads: B-NH1 (4).  stage: Ua(t+2) -> buf p
    load_B4<1>(Bb, wn, fr, kq, sw, b1);
    if (n2) { stageA(p, 0, kt + 2); stageA(p, 2, kt + 2); }
    SBAR();
    WAITLGKM();
    __builtin_amdgcn_s_setprio(1);
    mfma16<0, 1>(af, b1, acc);
    __builtin_amdgcn_s_setprio(0);
    __builtin_amdgcn_sched_barrier(0);
    SBAR();

    // ---- Phase 3: MH1 x NH0.  reads: A-MH1 (8).  stage: V01(t+2) -> buf p
    load_A8<1>(Ab, wm, fr, kq, sw, af);
    if (n2) { stageB(p, 0, kt + 2); stageB(p, 1, kt + 2); }
    SBAR();
    WAITLGKM();
    __builtin_amdgcn_s_setprio(1);
    mfma16<1, 0>(af, b0, acc);
    __builtin_amdgcn_s_setprio(0);
    __builtin_amdgcn_sched_barrier(0);
    SBAR();

    // ---- Phase 4: MH1 x NH1.  no reads.  stage: Ub(t+2) -> buf p
    if (n2) { stageA(p, 1, kt + 2); stageA(p, 3, kt + 2); }
    SBAR();
    __builtin_amdgcn_sched_barrier(0);
    __builtin_amdgcn_s_setprio(1);
    mfma16<1, 1>(af, b1, acc);
    __builtin_amdgcn_s_setprio(0);
    __builtin_amdgcn_sched_barrier(0);
    if (n2)      asm volatile("s_waitcnt vmcnt(6)" ::: "memory");
    else if (n1) asm volatile("s_waitcnt vmcnt(0)" ::: "memory");
    SBAR();
  };

  for (int kt = 0; kt < NT_SC; kt += 2) {
    tile(ic<0>{}, kt);
    tile(ic<1>{}, kt + 1);
  }

  // ---- epilogue
#pragma unroll
  for (int mf = 0; mf < 8; ++mf) {
#pragma unroll
    for (int nf = 0; nf < 4; ++nf) {
      const int r0 = brow + wm * 128 + mf * 16 + (lane >> 4) * 4;
      const int c  = bcol + wn * 64 + nf * 16 + (lane & 15);
#pragma unroll
      for (int r = 0; r < 4; ++r)
        C[(size_t)(r0 + r) * N_SEQ + c] = acc[mf][nf][r];
    }
  }
}

// ======================= fused hi/lo split =======================
struct SplitDesc {
  const float* src[7];
  bf16_t* hi[7];
  bf16_t* lo[7];
  int blk_start[8];
};

__global__ __launch_bounds__(256)
void split_all(SplitDesc d)
{
  const int b = blockIdx.x;
  int seg = 0;
#pragma unroll
  for (int s = 1; s < 7; ++s) seg += (b >= d.blk_start[s]) ? 1 : 0;
  const int i = (b - d.blk_start[seg]) * 256 + threadIdx.x;
  const float4 v = ((const float4*)d.src[seg])[i];
  const float vv[4] = {v.x, v.y, v.z, v.w};
  bf16x4 h, l;
#pragma unroll
  for (int j = 0; j < 4; ++j) {
    const bf16_t hh = (bf16_t)vv[j];
    h[j] = hh;
    l[j] = (bf16_t)(vv[j] - (float)hh);
  }
  ((bf16x4*)d.hi[seg])[i] = h;
  if (d.lo[seg]) ((bf16x4*)d.lo[seg])[i] = l;
}

// ======================= softmax =======================
__global__ __launch_bounds__(256)
void softmax_rows(float* __restrict__ S, bf16_t* __restrict__ P, int n)
{
  const int row = blockIdx.x;
  float* srow = S + (size_t)row * n;
  bf16_t* prow = P + (size_t)row * n;
  const int t = threadIdx.x;
  const int lane = t & 63;
  const int wave = t >> 6;
  __shared__ float red[8];

  float4 v[4];
  float mx = -3.4e38f;
#pragma unroll
  for (int i = 0; i < 4; ++i) {
    v[i] = *(const float4*)(srow + (size_t)(i * 256 + t) * 4);
    mx = fmaxf(mx, fmaxf(fmaxf(v[i].x, v[i].y), fmaxf(v[i].z, v[i].w)));
  }
#pragma unroll
  for (int off = 32; off > 0; off >>= 1) mx = fmaxf(mx, __shfl_xor(mx, off));
  if (lane == 0) red[wave] = mx;
  __syncthreads();
  mx = fmaxf(fmaxf(red[0], red[1]), fmaxf(red[2], red[3]));

  float e[16];
  float sum = 0.f;
#pragma unroll
  for (int i = 0; i < 4; ++i) {
    e[4 * i + 0] = __expf(v[i].x - mx);
    e[4 * i + 1] = __expf(v[i].y - mx);
    e[4 * i + 2] = __expf(v[i].z - mx);
    e[4 * i + 3] = __expf(v[i].w - mx);
    sum += e[4 * i + 0] + e[4 * i + 1] + e[4 * i + 2] + e[4 * i + 3];
  }
#pragma unroll
  for (int off = 32; off > 0; off >>= 1) sum += __shfl_xor(sum, off);
  if (lane == 0) red[4 + wave] = sum;
  __syncthreads();
  sum = red[4] + red[5] + red[6] + red[7];
  const float inv = 1.0f / sum;

#pragma unroll
  for (int i = 0; i < 4; ++i) {
    float4 w;
    w.x = e[4 * i + 0] * inv;
    w.y = e[4 * i + 1] * inv;
    w.z = e[4 * i + 2] * inv;
    w.w = e[4 * i + 3] * inv;
    *(float4*)(srow + (size_t)(i * 256 + t) * 4) = w;
    bf16x4 p;
    p[0] = (bf16_t)w.x;
    p[1] = (bf16_t)w.y;
    p[2] = (bf16_t)w.z;
    p[3] = (bf16_t)w.w;
    *(bf16x4*)(prow + (size_t)(i * 256 + t) * 4) = p;
  }
}

extern "C" void kernel_launch(void* const* d_in, const int* in_sizes, int n_in,
                              void* d_out, int out_size, void* d_ws, size_t ws_size,
                              hipStream_t stream) {
  const int N = N_SEQ, D = DMODEL;
  const float* q    = (const float*)d_in[0];
  const float* k    = (const float*)d_in[1];
  const float* v    = (const float*)d_in[2];
  const float* wq_w = (const float*)d_in[3];
  const float* wq_b = (const float*)d_in[4];
  const float* wk_w = (const float*)d_in[5];
  const float* wk_b = (const float*)d_in[6];
  const float* wv_w = (const float*)d_in[7];
  const float* wv_b = (const float*)d_in[8];
  const float* wo_w = (const float*)d_in[9];
  const float* wo_b = (const float*)d_in[10];

  float* x_out = (float*)d_out;                 // [N, D]
  float* attn  = x_out + (size_t)N * D;         // [N, N]

  char* wsp = (char*)d_ws;
  auto alloc = [&](size_t bytes) { char* p = wsp; wsp += bytes; return p; };
  const size_t ND = (size_t)N * D, DD = (size_t)D * D;
  bf16_t* q_hi  = (bf16_t*)alloc(ND * 2);
  bf16_t* q_lo  = (bf16_t*)alloc(ND * 2);
  bf16_t* k_hi  = (bf16_t*)alloc(ND * 2);
  bf16_t* k_lo  = (bf16_t*)alloc(ND * 2);
  bf16_t* v_hi  = (bf16_t*)alloc(ND * 2);
  bf16_t* wq_hi = (bf16_t*)alloc(DD * 2);
  bf16_t* wq_lo = (bf16_t*)alloc(DD * 2);
  bf16_t* wk_hi = (bf16_t*)alloc(DD * 2);
  bf16_t* wk_lo = (bf16_t*)alloc(DD * 2);
  bf16_t* wv_hi = (bf16_t*)alloc(DD * 2);
  bf16_t* wo_hi = (bf16_t*)alloc(DD * 2);
  bf16_t* QPhi  = (bf16_t*)alloc(ND * 2);
  bf16_t* QPlo  = (bf16_t*)alloc(ND * 2);
  bf16_t* KPhi  = (bf16_t*)alloc(ND * 2);
  bf16_t* KPlo  = (bf16_t*)alloc(ND * 2);
  bf16_t* VPt   = (bf16_t*)alloc(ND * 2);       // [D][N] transposed
  // aliases (producers run strictly after last readers of the underlying bufs)
  bf16_t* Pb    = QPhi;   // 32 MB over QPhi..KPlo (contiguous)
  bf16_t* Xb    = q_hi;   // 8 MB over q_hi

  // fused split: q,k -> hi+lo; v -> hi; wq,wk -> hi+lo; wv,wo -> hi
  SplitDesc sd;
  sd.src[0] = q;    sd.hi[0] = q_hi;  sd.lo[0] = q_lo;
  sd.src[1] = k;    sd.hi[1] = k_hi;  sd.lo[1] = k_lo;
  sd.src[2] = v;    sd.hi[2] = v_hi;  sd.lo[2] = nullptr;
  sd.src[3] = wq_w; sd.hi[3] = wq_hi; sd.lo[3] = wq_lo;
  sd.src[4] = wk_w; sd.hi[4] = wk_hi; sd.lo[4] = wk_lo;
  sd.src[5] = wv_w; sd.hi[5] = wv_hi; sd.lo[5] = nullptr;
  sd.src[6] = wo_w; sd.hi[6] = wo_hi; sd.lo[6] = nullptr;
  const int nb_nd = (int)(ND / 4 / 256);   // 4096
  const int nb_dd = (int)(DD / 4 / 256);   // 1024
  sd.blk_start[0] = 0;
  sd.blk_start[1] = nb_nd;
  sd.blk_start[2] = 2 * nb_nd;
  sd.blk_start[3] = 3 * nb_nd;
  sd.blk_start[4] = 3 * nb_nd + nb_dd;
  sd.blk_start[5] = 3 * nb_nd + 2 * nb_dd;
  sd.blk_start[6] = 3 * nb_nd + 3 * nb_dd;
  sd.blk_start[7] = 3 * nb_nd + 4 * nb_dd;
  split_all<<<dim3(sd.blk_start[7]), dim3(256), 0, stream>>>(sd);

  const dim3 blk(256);
  const dim3 gproj(D / BN, N / BM);    // (8, 32)
  const dim3 gsc(N / 256, N / 256);    // (16, 16)

  // Q projection (3-pass hi/lo precision)
  gemm_bt<3, EPI_HILO><<<gproj, blk, 0, stream>>>(
      q_hi, q_lo, wq_hi, wq_lo, wq_b, nullptr, QPhi, QPlo, N, D, D);

  // K projection (3-pass)
  gemm_bt<3, EPI_HILO><<<gproj, blk, 0, stream>>>(
      k_hi, k_lo, wk_hi, wk_lo, wk_b, nullptr, KPhi, KPlo, N, D, D);

  // V projection (1-pass; errors unamplified through softmax-avg)
  gemm_bt<1, EPI_BF16T><<<gproj, blk, 0, stream>>>(
      v_hi, nullptr, wv_hi, nullptr, wv_b, nullptr, VPt, nullptr, N, D, D);

  // scores = qp @ kp^T  (deep-pipelined 8-phase 256^2, logical K=3072)
  gemm8_scores<<<gsc, dim3(512), 0, stream>>>(QPhi, QPlo, KPhi, KPlo, attn);

  // softmax rows in-place + bf16 copy (Pb aliases QP/KP: they are dead now)
  softmax_rows<<<dim3(N), blk, 0, stream>>>(attn, Pb, N);

  // X = P @ VP
  gemm_bt<1, EPI_BF16><<<gproj, blk, 0, stream>>>(
      Pb, nullptr, VPt, nullptr, nullptr, nullptr, Xb, nullptr, N, D, N);

  // out = X @ wo^T + b
  gemm_bt<1, EPI_F32><<<gproj, blk, 0, stream>>>(
      Xb, nullptr, wo_hi, nullptr, wo_b, x_out, nullptr, nullptr, N, D, D);
}

// Round 4
// 384.702 us; speedup vs baseline: 1.1170x; 1.0083x over previous
//
#include <hip/hip_runtime.h>
#include <cstdint>

// Problem constants (fixed by the reference)
#define N_SEQ 4096
#define DMODEL 1024

#define BM 128
#define BN 128
#define BK 32

typedef __bf16 bf16_t;
typedef bf16_t bf16x8 __attribute__((ext_vector_type(8)));
typedef bf16_t bf16x4 __attribute__((ext_vector_type(4)));
typedef float f32x4 __attribute__((ext_vector_type(4)));

typedef __attribute__((address_space(1))) void* as1ptr;
typedef __attribute__((address_space(3))) void* as3ptr;

__device__ __forceinline__ void gload16(const bf16_t* g, bf16_t* l) {
  __builtin_amdgcn_global_load_lds((as1ptr)(uintptr_t)g, (as3ptr)(uintptr_t)l,
                                   16, 0, 0);
}

enum { EPI_F32 = 0, EPI_HILO = 1, EPI_BF16T = 2, EPI_BF16 = 3 };

// ======================= m97-structure 128x128 GEMM =======================
template <int PASSES, int EPI>
__global__ __launch_bounds__(256)
void gemm_bt(const bf16_t* __restrict__ Ahi, const bf16_t* __restrict__ Alo,
             const bf16_t* __restrict__ Bhi, const bf16_t* __restrict__ Blo,
             const float* __restrict__ bias,
             float* __restrict__ Cf, bf16_t* __restrict__ Cb,
             bf16_t* __restrict__ Cb2,
             int M, int Nc, int K)
{
  constexpr int NTILE = (PASSES == 3) ? 4 : 2;
  __shared__ __align__(16) bf16_t lds[NTILE * BM * BK];
  bf16_t* lAhi = lds;
  bf16_t* lBhi = lds + BM * BK;
  bf16_t* lAlo = (PASSES == 3) ? (lds + 2 * BM * BK) : nullptr;
  bf16_t* lBlo = (PASSES == 3) ? (lds + 3 * BM * BK) : nullptr;

  const int t = threadIdx.x;
  const int lane = t & 63;
  const int wave = t >> 6;
  const int wm = wave >> 1;
  const int wn = wave & 1;
  const int row0 = blockIdx.y * BM;
  const int col0 = blockIdx.x * BN;

  const int srow = t >> 2;
  const int scol = (t & 3) * 8;
  const int loff = srow * BK + scol;

  const int fr = lane & 15;
  const int kq = (lane >> 4) * 8;

  f32x4 acc[4][4] = {};

  for (int k0 = 0; k0 < K; k0 += BK) {
    const size_t ga = (size_t)(row0 + srow) * K + k0 + scol;
    const size_t gb = (size_t)(col0 + srow) * K + k0 + scol;
    gload16(Ahi + ga, lAhi + loff);
    gload16(Ahi + ga + (size_t)64 * K, lAhi + loff + 64 * BK);
    gload16(Bhi + gb, lBhi + loff);
    gload16(Bhi + gb + (size_t)64 * K, lBhi + loff + 64 * BK);
    if (PASSES == 3) {
      gload16(Alo + ga, lAlo + loff);
      gload16(Alo + ga + (size_t)64 * K, lAlo + loff + 64 * BK);
      gload16(Blo + gb, lBlo + loff);
      gload16(Blo + gb + (size_t)64 * K, lBlo + loff + 64 * BK);
    }
    __syncthreads();

    bf16x8 ah[4], bh[4], al[4], bl[4];
#pragma unroll
    for (int m = 0; m < 4; ++m)
      ah[m] = *(const bf16x8*)&lAhi[(wm * 64 + m * 16 + fr) * BK + kq];
#pragma unroll
    for (int n = 0; n < 4; ++n)
      bh[n] = *(const bf16x8*)&lBhi[(wn * 64 + n * 16 + fr) * BK + kq];
    if (PASSES == 3) {
#pragma unroll
      for (int m = 0; m < 4; ++m)
        al[m] = *(const bf16x8*)&lAlo[(wm * 64 + m * 16 + fr) * BK + kq];
#pragma unroll
      for (int n = 0; n < 4; ++n)
        bl[n] = *(const bf16x8*)&lBlo[(wn * 64 + n * 16 + fr) * BK + kq];
    }

#pragma unroll
    for (int m = 0; m < 4; ++m)
#pragma unroll
      for (int n = 0; n < 4; ++n) {
        acc[m][n] =
            __builtin_amdgcn_mfma_f32_16x16x32_bf16(ah[m], bh[n], acc[m][n], 0, 0, 0);
        if (PASSES == 3) {
          acc[m][n] =
              __builtin_amdgcn_mfma_f32_16x16x32_bf16(ah[m], bl[n], acc[m][n], 0, 0, 0);
          acc[m][n] =
              __builtin_amdgcn_mfma_f32_16x16x32_bf16(al[m], bh[n], acc[m][n], 0, 0, 0);
        }
      }
    __syncthreads();
  }

#pragma unroll
  for (int m = 0; m < 4; ++m) {
#pragma unroll
    for (int n = 0; n < 4; ++n) {
      const int grow0 = row0 + wm * 64 + m * 16 + (lane >> 4) * 4;
      const int gcol = col0 + wn * 64 + n * 16 + (lane & 15);
      const float bv = bias ? bias[gcol] : 0.0f;
      if (EPI == EPI_BF16T) {
        bf16x4 p;
#pragma unroll
        for (int r = 0; r < 4; ++r) p[r] = (bf16_t)(acc[m][n][r] + bv);
        *(bf16x4*)&Cb[(size_t)gcol * M + grow0] = p;
      } else {
#pragma unroll
        for (int r = 0; r < 4; ++r) {
          const float val = acc[m][n][r] + bv;
          const size_t idx = (size_t)(grow0 + r) * Nc + gcol;
          if (EPI == EPI_F32) {
            Cf[idx] = val;
          } else if (EPI == EPI_HILO) {
            const bf16_t h = (bf16_t)val;
            Cb[idx] = h;
            Cb2[idx] = (bf16_t)(val - (float)h);
          } else {
            Cb[idx] = (bf16_t)val;
          }
        }
      }
    }
  }
}

// ======================= 8-phase 256x256 scores GEMM (v4) =======================
// v4: counted-lgkmcnt ds_read pipelining — phase i's MFMA overlaps phase i+1's
// LDS reads in the same wave; one barrier per phase (placed exactly at the
// stage-safety points). Staging cadence and vmcnt(6) depth unchanged from v3.
#define TILE_ELEMS 16384   // 256 rows x 64 cols
#define UNIT_ELEMS 4096    // 64 rows x 64 cols
#define NT_SC 48

template <int V> struct ic { static constexpr int value = V; };

#define SBAR() asm volatile("s_barrier" ::: "memory")
#define WAITLGKM(n)                                              \
  do {                                                           \
    asm volatile("s_waitcnt lgkmcnt(" #n ")" ::: "memory");      \
    __builtin_amdgcn_sched_barrier(0);                           \
  } while (0)

template <int MH>
__device__ __forceinline__ void load_A8(const bf16_t* Ab, int wm, int fr,
                                        int kq, int sw, bf16x8 (&af)[4][2]) {
#pragma unroll
  for (int m = 0; m < 4; ++m) {
    const int row = wm * 128 + (MH * 4 + m) * 16 + fr;
#pragma unroll
    for (int ks = 0; ks < 2; ++ks)
      af[m][ks] = *(const bf16x8*)&Ab[row * 64 + ((ks * 32 + kq) ^ sw)];
  }
}

template <int NH>
__device__ __forceinline__ void load_B4(const bf16_t* Bb, int wn, int fr,
                                        int kq, int sw, bf16x8 (&bfr)[2][2]) {
#pragma unroll
  for (int n = 0; n < 2; ++n) {
    const int row = wn * 64 + (NH * 2 + n) * 16 + fr;
#pragma unroll
    for (int ks = 0; ks < 2; ++ks)
      bfr[n][ks] = *(const bf16x8*)&Bb[row * 64 + ((ks * 32 + kq) ^ sw)];
  }
}

template <int MH, int NH>
__device__ __forceinline__ void mfma16(const bf16x8 (&af)[4][2],
                                       const bf16x8 (&bfr)[2][2],
                                       f32x4 (&acc)[8][4]) {
#pragma unroll
  for (int m = 0; m < 4; ++m)
#pragma unroll
    for (int n = 0; n < 2; ++n)
#pragma unroll
      for (int ks = 0; ks < 2; ++ks)
        acc[MH * 4 + m][NH * 2 + n] = __builtin_amdgcn_mfma_f32_16x16x32_bf16(
            af[m][ks], bfr[n][ks], acc[MH * 4 + m][NH * 2 + n], 0, 0, 0);
}

__global__ __launch_bounds__(512, 2)
void gemm8_scores(const bf16_t* __restrict__ Ahi, const bf16_t* __restrict__ Alo,
                  const bf16_t* __restrict__ Bhi, const bf16_t* __restrict__ Blo,
                  float* __restrict__ C)
{
  __shared__ __align__(16) bf16_t sm[2 * 2 * TILE_ELEMS];  // 128 KiB

  const int t = threadIdx.x;
  const int lane = t & 63;
  const int wave = t >> 6;
  const int wm = wave >> 2;      // 0..1
  const int wn = wave & 3;       // 0..3
  const int brow = blockIdx.y * 256;
  const int bcol = blockIdx.x * 256;

  // staging: thread t covers linear dest elems [t*8, t*8+8) within a unit;
  // pre-swizzled source column (involution with the read-side XOR).
  const int srow = t >> 3;                               // 0..63
  const int scol = 8 * ((t & 7) ^ ((t >> 3) & 7));       // pre-swizzled src col
  const int sdst = t * 8;

  const int fr = lane & 15;
  const int kq = (lane >> 4) * 8;
  const int sw = (fr & 7) << 3;                          // read-side swizzle

  auto stageA = [&](int buf, int u, int kt) {
    const int seg = kt >> 4;                 // 0,1 -> hi ; 2 -> lo
    const bf16_t* src = (seg == 2) ? Alo : Ahi;
    const int kk = (kt & 15) << 6;
    gload16(src + (size_t)(brow + u * 64 + srow) * DMODEL + kk + scol,
            &sm[(buf * 2 + 0) * TILE_ELEMS + u * UNIT_ELEMS + sdst]);
  };
  auto stageB = [&](int buf, int u, int kt) {
    const int seg = kt >> 4;                 // 0,2 -> hi ; 1 -> lo
    const bf16_t* src = (seg == 1) ? Blo : Bhi;
    const int kk = (kt & 15) << 6;
    gload16(src + (size_t)(bcol + u * 64 + srow) * DMODEL + kk + scol,
            &sm[(buf * 2 + 1) * TILE_ELEMS + u * UNIT_ELEMS + sdst]);
  };

  f32x4 acc[8][4] = {};
  bf16x8 af0[4][2], af1[4][2];   // A MH0 / MH1 fragment sets
  bf16x8 b0[2][2], b1[2][2];     // B NH0 / NH1 fragment sets

  // ---- prologue: tile0 all 8 units; tile1's Ua, V01, Ub (6 loads).
#pragma unroll
  for (int u = 0; u < 4; ++u) stageA(0, u, 0);
#pragma unroll
  for (int u = 0; u < 4; ++u) stageB(0, u, 0);
  stageA(1, 0, 1); stageA(1, 2, 1);   // Ua(1)
  stageB(1, 0, 1); stageB(1, 1, 1);   // V01(1)
  stageA(1, 1, 1); stageA(1, 3, 1);   // Ub(1)
  asm volatile("s_waitcnt vmcnt(6)" ::: "memory");  // tile0's 8 landed
  SBAR();

  auto tile = [&](auto Pc, int kt) {
    constexpr int p = decltype(Pc)::value;
    constexpr int q = p ^ 1;
    const bool n1 = (kt + 1 < NT_SC);
    const bool n2 = (kt + 2 < NT_SC);
    const bf16_t* Ab = &sm[(p * 2 + 0) * TILE_ELEMS];
    const bf16_t* Bb = &sm[(p * 2 + 1) * TILE_ELEMS];

    // ---- Phase 1: MFMA(MH0,NH0).
    // reads R1 = A-MH0(8) + B-NH0(4); pipelined R2 = B-NH1(4).
    // stage: V23(t+1) -> buf q.
    load_A8<0>(Ab, wm, fr, kq, sw, af0);
    load_B4<0>(Bb, wn, fr, kq, sw, b0);
    if (n1) { stageB(q, 2, kt + 1); stageB(q, 3, kt + 1); }
    load_B4<1>(Bb, wn, fr, kq, sw, b1);
    WAITLGKM(4);                      // R1 drained; R2 in flight
    __builtin_amdgcn_s_setprio(1);
    mfma16<0, 0>(af0, b0, acc);
    __builtin_amdgcn_s_setprio(0);
    __builtin_amdgcn_sched_barrier(0);
    SBAR();  // A: all waves' R1 (incl. A-U0/U2 reads) complete

    // ---- Phase 2: MFMA(MH0,NH1).
    // pipelined R3 = A-MH1(8) into af1.  stage: Ua(t+2) -> buf p (U0,U2).
    if (n2) { stageA(p, 0, kt + 2); stageA(p, 2, kt + 2); }
    load_A8<1>(Ab, wm, fr, kq, sw, af1);
    WAITLGKM(8);                      // R2 drained; R3 in flight
    __builtin_amdgcn_s_setprio(1);
    mfma16<0, 1>(af0, b1, acc);
    __builtin_amdgcn_s_setprio(0);
    __builtin_amdgcn_sched_barrier(0);
    SBAR();  // B: all waves' R2 (B-V reads) complete

    // ---- Phase 3: MFMA(MH1,NH0).  stage: V01(t+2) -> buf p.
    if (n2) { stageB(p, 0, kt + 2); stageB(p, 1, kt + 2); }
    WAITLGKM(0);                      // R3 drained
    __builtin_amdgcn_s_setprio(1);
    mfma16<1, 0>(af1, b0, acc);
    __builtin_amdgcn_s_setprio(0);
    __builtin_amdgcn_sched_barrier(0);
    SBAR();  // C: all waves' R3 (A-U1/U3 reads) complete

    // ---- Phase 4: MFMA(MH1,NH1).  stage: Ub(t+2) -> buf p.  no reads.
    if (n2) { stageA(p, 1, kt + 2); stageA(p, 3, kt + 2); }
    __builtin_amdgcn_s_setprio(1);
    mfma16<1, 1>(af1, b1, acc);
    __builtin_amdgcn_s_setprio(0);
    __builtin_amdgcn_sched_barrier(0);
    if (n2)      asm volatile("s_waitcnt vmcnt(6)" ::: "memory");
    else if (n1) asm volatile("s_waitcnt vmcnt(0)" ::: "memory");
    SBAR();  // tile boundary: tile t+1 fully staged
  };

  for (int kt = 0; kt < NT_SC; kt += 2) {
    tile(ic<0>{}, kt);
    tile(ic<1>{}, kt + 1);
  }

  // ---- epilogue
#pragma unroll
  for (int mf = 0; mf < 8; ++mf) {
#pragma unroll
    for (int nf = 0; nf < 4; ++nf) {
      const int r0 = brow + wm * 128 + mf * 16 + (lane >> 4) * 4;
      const int c  = bcol + wn * 64 + nf * 16 + (lane & 15);
#pragma unroll
      for (int r = 0; r < 4; ++r)
        C[(size_t)(r0 + r) * N_SEQ + c] = acc[mf][nf][r];
    }
  }
}

// ======================= fused hi/lo split =======================
struct SplitDesc {
  const float* src[7];
  bf16_t* hi[7];
  bf16_t* lo[7];
  int blk_start[8];
};

__global__ __launch_bounds__(256)
void split_all(SplitDesc d)
{
  const int b = blockIdx.x;
  int seg = 0;
#pragma unroll
  for (int s = 1; s < 7; ++s) seg += (b >= d.blk_start[s]) ? 1 : 0;
  const int i = (b - d.blk_start[seg]) * 256 + threadIdx.x;
  const float4 v = ((const float4*)d.src[seg])[i];
  const float vv[4] = {v.x, v.y, v.z, v.w};
  bf16x4 h, l;
#pragma unroll
  for (int j = 0; j < 4; ++j) {
    const bf16_t hh = (bf16_t)vv[j];
    h[j] = hh;
    l[j] = (bf16_t)(vv[j] - (float)hh);
  }
  ((bf16x4*)d.hi[seg])[i] = h;
  if (d.lo[seg]) ((bf16x4*)d.lo[seg])[i] = l;
}

// ======================= softmax =======================
__global__ __launch_bounds__(256)
void softmax_rows(float* __restrict__ S, bf16_t* __restrict__ P, int n)
{
  const int row = blockIdx.x;
  float* srow = S + (size_t)row * n;
  bf16_t* prow = P + (size_t)row * n;
  const int t = threadIdx.x;
  const int lane = t & 63;
  const int wave = t >> 6;
  __shared__ float red[8];

  float4 v[4];
  float mx = -3.4e38f;
#pragma unroll
  for (int i = 0; i < 4; ++i) {
    v[i] = *(const float4*)(srow + (size_t)(i * 256 + t) * 4);
    mx = fmaxf(mx, fmaxf(fmaxf(v[i].x, v[i].y), fmaxf(v[i].z, v[i].w)));
  }
#pragma unroll
  for (int off = 32; off > 0; off >>= 1) mx = fmaxf(mx, __shfl_xor(mx, off));
  if (lane == 0) red[wave] = mx;
  __syncthreads();
  mx = fmaxf(fmaxf(red[0], red[1]), fmaxf(red[2], red[3]));

  float e[16];
  float sum = 0.f;
#pragma unroll
  for (int i = 0; i < 4; ++i) {
    e[4 * i + 0] = __expf(v[i].x - mx);
    e[4 * i + 1] = __expf(v[i].y - mx);
    e[4 * i + 2] = __expf(v[i].z - mx);
    e[4 * i + 3] = __expf(v[i].w - mx);
    sum += e[4 * i + 0] + e[4 * i + 1] + e[4 * i + 2] + e[4 * i + 3];
  }
#pragma unroll
  for (int off = 32; off > 0; off >>= 1) sum += __shfl_xor(sum, off);
  if (lane == 0) red[4 + wave] = sum;
  __syncthreads();
  sum = red[4] + red[5] + red[6] + red[7];
  const float inv = 1.0f / sum;

#pragma unroll
  for (int i = 0; i < 4; ++i) {
    float4 w;
    w.x = e[4 * i + 0] * inv;
    w.y = e[4 * i + 1] * inv;
    w.z = e[4 * i + 2] * inv;
    w.w = e[4 * i + 3] * inv;
    *(float4*)(srow + (size_t)(i * 256 + t) * 4) = w;
    bf16x4 p;
    p[0] = (bf16_t)w.x;
    p[1] = (bf16_t)w.y;
    p[2] = (bf16_t)w.z;
    p[3] = (bf16_t)w.w;
    *(bf16x4*)(prow + (size_t)(i * 256 + t) * 4) = p;
  }
}

extern "C" void kernel_launch(void* const* d_in, const int* in_sizes, int n_in,
                              void* d_out, int out_size, void* d_ws, size_t ws_size,
                              hipStream_t stream) {
  const int N = N_SEQ, D = DMODEL;
  const float* q    = (const float*)d_in[0];
  const float* k    = (const float*)d_in[1];
  const float* v    = (const float*)d_in[2];
  const float* wq_w = (const float*)d_in[3];
  const float* wq_b = (const float*)d_in[4];
  const float* wk_w = (const float*)d_in[5];
  const float* wk_b = (const float*)d_in[6];
  const float* wv_w = (const float*)d_in[7];
  const float* wv_b = (const float*)d_in[8];
  const float* wo_w = (const float*)d_in[9];
  const float* wo_b = (const float*)d_in[10];

  float* x_out = (float*)d_out;                 // [N, D]
  float* attn  = x_out + (size_t)N * D;         // [N, N]

  char* wsp = (char*)d_ws;
  auto alloc = [&](size_t bytes) { char* p = wsp; wsp += bytes; return p; };
  const size_t ND = (size_t)N * D, DD = (size_t)D * D;
  bf16_t* q_hi  = (bf16_t*)alloc(ND * 2);
  bf16_t* q_lo  = (bf16_t*)alloc(ND * 2);
  bf16_t* k_hi  = (bf16_t*)alloc(ND * 2);
  bf16_t* k_lo  = (bf16_t*)alloc(ND * 2);
  bf16_t* v_hi  = (bf16_t*)alloc(ND * 2);
  bf16_t* wq_hi = (bf16_t*)alloc(DD * 2);
  bf16_t* wq_lo = (bf16_t*)alloc(DD * 2);
  bf16_t* wk_hi = (bf16_t*)alloc(DD * 2);
  bf16_t* wk_lo = (bf16_t*)alloc(DD * 2);
  bf16_t* wv_hi = (bf16_t*)alloc(DD * 2);
  bf16_t* wo_hi = (bf16_t*)alloc(DD * 2);
  bf16_t* QPhi  = (bf16_t*)alloc(ND * 2);
  bf16_t* QPlo  = (bf16_t*)alloc(ND * 2);
  bf16_t* KPhi  = (bf16_t*)alloc(ND * 2);
  bf16_t* KPlo  = (bf16_t*)alloc(ND * 2);
  bf16_t* VPt   = (bf16_t*)alloc(ND * 2);       // [D][N] transposed
  // aliases (producers run strictly after last readers of the underlying bufs)
  bf16_t* Pb    = QPhi;   // 32 MB over QPhi..KPlo (contiguous)
  bf16_t* Xb    = q_hi;   // 8 MB over q_hi

  // fused split: q,k -> hi+lo; v -> hi; wq,wk -> hi+lo; wv,wo -> hi
  SplitDesc sd;
  sd.src[0] = q;    sd.hi[0] = q_hi;  sd.lo[0] = q_lo;
  sd.src[1] = k;    sd.hi[1] = k_hi;  sd.lo[1] = k_lo;
  sd.src[2] = v;    sd.hi[2] = v_hi;  sd.lo[2] = nullptr;
  sd.src[3] = wq_w; sd.hi[3] = wq_hi; sd.lo[3] = wq_lo;
  sd.src[4] = wk_w; sd.hi[4] = wk_hi; sd.lo[4] = wk_lo;
  sd.src[5] = wv_w; sd.hi[5] = wv_hi; sd.lo[5] = nullptr;
  sd.src[6] = wo_w; sd.hi[6] = wo_hi; sd.lo[6] = nullptr;
  const int nb_nd = (int)(ND / 4 / 256);   // 4096
  const int nb_dd = (int)(DD / 4 / 256);   // 1024
  sd.blk_start[0] = 0;
  sd.blk_start[1] = nb_nd;
  sd.blk_start[2] = 2 * nb_nd;
  sd.blk_start[3] = 3 * nb_nd;
  sd.blk_start[4] = 3 * nb_nd + nb_dd;
  sd.blk_start[5] = 3 * nb_nd + 2 * nb_dd;
  sd.blk_start[6] = 3 * nb_nd + 3 * nb_dd;
  sd.blk_start[7] = 3 * nb_nd + 4 * nb_dd;
  split_all<<<dim3(sd.blk_start[7]), dim3(256), 0, stream>>>(sd);

  const dim3 blk(256);
  const dim3 gproj(D / BN, N / BM);    // (8, 32)
  const dim3 gsc(N / 256, N / 256);    // (16, 16)

  // Q projection (3-pass hi/lo precision)
  gemm_bt<3, EPI_HILO><<<gproj, blk, 0, stream>>>(
      q_hi, q_lo, wq_hi, wq_lo, wq_b, nullptr, QPhi, QPlo, N, D, D);

  // K projection (3-pass)
  gemm_bt<3, EPI_HILO><<<gproj, blk, 0, stream>>>(
      k_hi, k_lo, wk_hi, wk_lo, wk_b, nullptr, KPhi, KPlo, N, D, D);

  // V projection (1-pass; errors unamplified through softmax-avg)
  gemm_bt<1, EPI_BF16T><<<gproj, blk, 0, stream>>>(
      v_hi, nullptr, wv_hi, nullptr, wv_b, nullptr, VPt, nullptr, N, D, D);

  // scores = qp @ kp^T  (pipelined 8-phase 256^2, logical K=3072)
  gemm8_scores<<<gsc, dim3(512), 0, stream>>>(QPhi, QPlo, KPhi, KPlo, attn);

  // softmax rows in-place + bf16 copy (Pb aliases QP/KP: they are dead now)
  softmax_rows<<<dim3(N), blk, 0, stream>>>(attn, Pb, N);

  // X = P @ VP
  gemm_bt<1, EPI_BF16><<<gproj, blk, 0, stream>>>(
      Pb, nullptr, VPt, nullptr, nullptr, nullptr, Xb, nullptr, N, D, N);

  // out = X @ wo^T + b
  gemm_bt<1, EPI_F32><<<gproj, blk, 0, stream>>>(
      Xb, nullptr, wo_hi, nullptr, wo_b, x_out, nullptr, nullptr, N, D, D);
}

// Round 6
// 358.510 us; speedup vs baseline: 1.1986x; 1.0731x over previous
//
#include <hip/hip_runtime.h>
#include <cstdint>

// Problem constants (fixed by the reference)
#define N_SEQ 4096
#define DMODEL 1024

#define BM 128
#define BN 128
#define BK 32

typedef __bf16 bf16_t;
typedef _Float16 f16_t;
typedef bf16_t bf16x8 __attribute__((ext_vector_type(8)));
typedef bf16_t bf16x4 __attribute__((ext_vector_type(4)));
typedef f16_t f16x8 __attribute__((ext_vector_type(8)));
typedef float f32x4 __attribute__((ext_vector_type(4)));

typedef __attribute__((address_space(1))) void* as1ptr;
typedef __attribute__((address_space(3))) void* as3ptr;

__device__ __forceinline__ void gload16(const void* g, void* l) {
  __builtin_amdgcn_global_load_lds((as1ptr)(uintptr_t)g, (as3ptr)(uintptr_t)l,
                                   16, 0, 0);
}

enum { EPI_F32 = 0, EPI_HILO = 1, EPI_BF16T = 2, EPI_BF16 = 3,
       EPI_HILO16 = 4, EPI_F16 = 5 };

// ======================= m97-structure 128x128 GEMM =======================
template <int PASSES, int EPI>
__global__ __launch_bounds__(256)
void gemm_bt(const bf16_t* __restrict__ Ahi, const bf16_t* __restrict__ Alo,
             const bf16_t* __restrict__ Bhi, const bf16_t* __restrict__ Blo,
             const float* __restrict__ bias,
             float* __restrict__ Cf, bf16_t* __restrict__ Cb,
             bf16_t* __restrict__ Cb2,
             int M, int Nc, int K)
{
  constexpr int NTILE = (PASSES == 3) ? 4 : 2;
  __shared__ __align__(16) bf16_t lds[NTILE * BM * BK];
  bf16_t* lAhi = lds;
  bf16_t* lBhi = lds + BM * BK;
  bf16_t* lAlo = (PASSES == 3) ? (lds + 2 * BM * BK) : nullptr;
  bf16_t* lBlo = (PASSES == 3) ? (lds + 3 * BM * BK) : nullptr;

  const int t = threadIdx.x;
  const int lane = t & 63;
  const int wave = t >> 6;
  const int wm = wave >> 1;
  const int wn = wave & 1;
  const int row0 = blockIdx.y * BM;
  const int col0 = blockIdx.x * BN;

  const int srow = t >> 2;
  const int scol = (t & 3) * 8;
  const int loff = srow * BK + scol;

  const int fr = lane & 15;
  const int kq = (lane >> 4) * 8;

  f32x4 acc[4][4] = {};

  for (int k0 = 0; k0 < K; k0 += BK) {
    const size_t ga = (size_t)(row0 + srow) * K + k0 + scol;
    const size_t gb = (size_t)(col0 + srow) * K + k0 + scol;
    gload16(Ahi + ga, lAhi + loff);
    gload16(Ahi + ga + (size_t)64 * K, lAhi + loff + 64 * BK);
    gload16(Bhi + gb, lBhi + loff);
    gload16(Bhi + gb + (size_t)64 * K, lBhi + loff + 64 * BK);
    if (PASSES == 3) {
      gload16(Alo + ga, lAlo + loff);
      gload16(Alo + ga + (size_t)64 * K, lAlo + loff + 64 * BK);
      gload16(Blo + gb, lBlo + loff);
      gload16(Blo + gb + (size_t)64 * K, lBlo + loff + 64 * BK);
    }
    __syncthreads();

    bf16x8 ah[4], bh[4], al[4], bl[4];
#pragma unroll
    for (int m = 0; m < 4; ++m)
      ah[m] = *(const bf16x8*)&lAhi[(wm * 64 + m * 16 + fr) * BK + kq];
#pragma unroll
    for (int n = 0; n < 4; ++n)
      bh[n] = *(const bf16x8*)&lBhi[(wn * 64 + n * 16 + fr) * BK + kq];
    if (PASSES == 3) {
#pragma unroll
      for (int m = 0; m < 4; ++m)
        al[m] = *(const bf16x8*)&lAlo[(wm * 64 + m * 16 + fr) * BK + kq];
#pragma unroll
      for (int n = 0; n < 4; ++n)
        bl[n] = *(const bf16x8*)&lBlo[(wn * 64 + n * 16 + fr) * BK + kq];
    }

#pragma unroll
    for (int m = 0; m < 4; ++m)
#pragma unroll
      for (int n = 0; n < 4; ++n) {
        acc[m][n] =
            __builtin_amdgcn_mfma_f32_16x16x32_bf16(ah[m], bh[n], acc[m][n], 0, 0, 0);
        if (PASSES == 3) {
          acc[m][n] =
              __builtin_amdgcn_mfma_f32_16x16x32_bf16(ah[m], bl[n], acc[m][n], 0, 0, 0);
          acc[m][n] =
              __builtin_amdgcn_mfma_f32_16x16x32_bf16(al[m], bh[n], acc[m][n], 0, 0, 0);
        }
      }
    __syncthreads();
  }

#pragma unroll
  for (int m = 0; m < 4; ++m) {
#pragma unroll
    for (int n = 0; n < 4; ++n) {
      const int grow0 = row0 + wm * 64 + m * 16 + (lane >> 4) * 4;
      const int gcol = col0 + wn * 64 + n * 16 + (lane & 15);
      const float bv = bias ? bias[gcol] : 0.0f;
      if (EPI == EPI_BF16T) {
        bf16x4 p;
#pragma unroll
        for (int r = 0; r < 4; ++r) p[r] = (bf16_t)(acc[m][n][r] + bv);
        *(bf16x4*)&Cb[(size_t)gcol * M + grow0] = p;
      } else {
#pragma unroll
        for (int r = 0; r < 4; ++r) {
          const float val = acc[m][n][r] + bv;
          const size_t idx = (size_t)(grow0 + r) * Nc + gcol;
          if (EPI == EPI_F32) {
            Cf[idx] = val;
          } else if (EPI == EPI_HILO) {
            const bf16_t h = (bf16_t)val;
            Cb[idx] = h;
            Cb2[idx] = (bf16_t)(val - (float)h);
          } else if (EPI == EPI_BF16) {
            Cb[idx] = (bf16_t)val;
          } else if (EPI == EPI_HILO16) {
            f16_t* Ch  = (f16_t*)Cb;
            f16_t* Ch2 = (f16_t*)Cb2;
            const f16_t h = (f16_t)val;
            Ch[idx] = h;
            Ch2[idx] = (f16_t)(val - (float)h);
          } else {  // EPI_F16
            ((f16_t*)Cb)[idx] = (f16_t)val;
          }
        }
      }
    }
  }
}

// ============ fp16 2-pass 256x256 scores GEMM (R4 structure) ============
// scores = (Qh+Ql) @ Kh^T as single-pass fp16 GEMM with logical K = 2*1024:
// kt 0-15 -> Qh*Kh, kt 16-31 -> Ql*Kh.  LDS: 2 mats x 2 bufs = 128 KiB.
// Schedule identical to R4 (counted-lgkm pipelined reads, vmcnt(6) staging).
#define TILE_ELEMS 16384   // 256 rows x 64 cols
#define UNIT_ELEMS 4096    // 64 rows x 64 cols
#define NT_SC 32

template <int V> struct ic { static constexpr int value = V; };

#define SBAR() asm volatile("s_barrier" ::: "memory")
#define WAITLGKM(n)                                              \
  do {                                                           \
    asm volatile("s_waitcnt lgkmcnt(" #n ")" ::: "memory");      \
    __builtin_amdgcn_sched_barrier(0);                           \
  } while (0)

template <int MH>
__device__ __forceinline__ void load_A8f(const f16_t* Ab, int wm, int fr,
                                         int kq, int sw, f16x8 (&af)[4][2]) {
#pragma unroll
  for (int m = 0; m < 4; ++m) {
    const int row = wm * 128 + (MH * 4 + m) * 16 + fr;
#pragma unroll
    for (int ks = 0; ks < 2; ++ks)
      af[m][ks] = *(const f16x8*)&Ab[row * 64 + ((ks * 32 + kq) ^ sw)];
  }
}

template <int NH>
__device__ __forceinline__ void load_B4f(const f16_t* Bb, int wn, int fr,
                                         int kq, int sw, f16x8 (&bfr)[2][2]) {
#pragma unroll
  for (int n = 0; n < 2; ++n) {
    const int row = wn * 64 + (NH * 2 + n) * 16 + fr;
#pragma unroll
    for (int ks = 0; ks < 2; ++ks)
      bfr[n][ks] = *(const f16x8*)&Bb[row * 64 + ((ks * 32 + kq) ^ sw)];
  }
}

template <int MH, int NH>
__device__ __forceinline__ void mfma16f(const f16x8 (&af)[4][2],
                                        const f16x8 (&bfr)[2][2],
                                        f32x4 (&acc)[8][4]) {
#pragma unroll
  for (int m = 0; m < 4; ++m)
#pragma unroll
    for (int n = 0; n < 2; ++n)
#pragma unroll
      for (int ks = 0; ks < 2; ++ks)
        acc[MH * 4 + m][NH * 2 + n] = __builtin_amdgcn_mfma_f32_16x16x32_f16(
            af[m][ks], bfr[n][ks], acc[MH * 4 + m][NH * 2 + n], 0, 0, 0);
}

__global__ __launch_bounds__(512, 2)
void gemm8f_scores(const f16_t* __restrict__ Qh, const f16_t* __restrict__ Ql,
                   const f16_t* __restrict__ Kh, float* __restrict__ C)
{
  __shared__ __align__(16) f16_t sm[2 * 2 * TILE_ELEMS];  // 128 KiB

  const int t = threadIdx.x;
  const int lane = t & 63;
  const int wave = t >> 6;
  const int wm = wave >> 2;      // 0..1
  const int wn = wave & 3;       // 0..3

  // XCD-aware block swizzle: grid 16x16 = 256 blocks, 256 = 8*32 (bijective)
  const int flat = blockIdx.y * 16 + blockIdx.x;
  const int swzb = (flat & 7) * 32 + (flat >> 3);
  const int brow = (swzb >> 4) * 256;
  const int bcol = (swzb & 15) * 256;

  // staging: thread t -> linear dest [t*8, t*8+8) in a unit; pre-swizzled src
  const int srow = t >> 3;                               // 0..63
  const int scol = 8 * ((t & 7) ^ ((t >> 3) & 7));       // involution
  const int sdst = t * 8;

  const int fr = lane & 15;
  const int kq = (lane >> 4) * 8;
  const int sw = (fr & 7) << 3;                          // read-side swizzle

  auto stageA = [&](int buf, int u, int kt) {
    const f16_t* src = (kt >= 16) ? Ql : Qh;
    const int kk = (kt & 15) << 6;
    gload16(src + (size_t)(brow + u * 64 + srow) * DMODEL + kk + scol,
            &sm[(buf * 2 + 0) * TILE_ELEMS + u * UNIT_ELEMS + sdst]);
  };
  auto stageB = [&](int buf, int u, int kt) {
    const int kk = (kt & 15) << 6;
    gload16(Kh + (size_t)(bcol + u * 64 + srow) * DMODEL + kk + scol,
            &sm[(buf * 2 + 1) * TILE_ELEMS + u * UNIT_ELEMS + sdst]);
  };

  f32x4 acc[8][4] = {};
  f16x8 af0[4][2], af1[4][2];   // A MH0 / MH1 fragment sets
  f16x8 b0[2][2], b1[2][2];     // B NH0 / NH1 fragment sets

  // ---- prologue: tile0 all 8 units; tile1's Ua, V01, Ub (6 loads).
#pragma unroll
  for (int u = 0; u < 4; ++u) stageA(0, u, 0);
#pragma unroll
  for (int u = 0; u < 4; ++u) stageB(0, u, 0);
  stageA(1, 0, 1); stageA(1, 2, 1);   // Ua(1)
  stageB(1, 0, 1); stageB(1, 1, 1);   // V01(1)
  stageA(1, 1, 1); stageA(1, 3, 1);   // Ub(1)
  asm volatile("s_waitcnt vmcnt(6)" ::: "memory");  // tile0's 8 landed
  SBAR();

  auto tile = [&](auto Pc, int kt) {
    constexpr int p = decltype(Pc)::value;
    constexpr int q = p ^ 1;
    const bool n1 = (kt + 1 < NT_SC);
    const bool n2 = (kt + 2 < NT_SC);
    const f16_t* Ab = &sm[(p * 2 + 0) * TILE_ELEMS];
    const f16_t* Bb = &sm[(p * 2 + 1) * TILE_ELEMS];

    // ---- Phase 1: MFMA(MH0,NH0).
    // reads R1 = A-MH0(8) + B-NH0(4); pipelined R2 = B-NH1(4).
    // stage: V23(t+1) -> buf q.
    load_A8f<0>(Ab, wm, fr, kq, sw, af0);
    load_B4f<0>(Bb, wn, fr, kq, sw, b0);
    if (n1) { stageB(q, 2, kt + 1); stageB(q, 3, kt + 1); }
    load_B4f<1>(Bb, wn, fr, kq, sw, b1);
    WAITLGKM(4);                      // R1 drained; R2 in flight
    __builtin_amdgcn_s_setprio(1);
    mfma16f<0, 0>(af0, b0, acc);
    __builtin_amdgcn_s_setprio(0);
    __builtin_amdgcn_sched_barrier(0);
    SBAR();

    // ---- Phase 2: MFMA(MH0,NH1).
    // pipelined R3 = A-MH1(8) into af1.  stage: Ua(t+2) -> buf p (U0,U2).
    if (n2) { stageA(p, 0, kt + 2); stageA(p, 2, kt + 2); }
    load_A8f<1>(Ab, wm, fr, kq, sw, af1);
    WAITLGKM(8);                      // R2 drained; R3 in flight
    __builtin_amdgcn_s_setprio(1);
    mfma16f<0, 1>(af0, b1, acc);
    __builtin_amdgcn_s_setprio(0);
    __builtin_amdgcn_sched_barrier(0);
    SBAR();

    // ---- Phase 3: MFMA(MH1,NH0).  stage: V01(t+2) -> buf p.
    if (n2) { stageB(p, 0, kt + 2); stageB(p, 1, kt + 2); }
    WAITLGKM(0);                      // R3 drained
    __builtin_amdgcn_s_setprio(1);
    mfma16f<1, 0>(af1, b0, acc);
    __builtin_amdgcn_s_setprio(0);
    __builtin_amdgcn_sched_barrier(0);
    SBAR();

    // ---- Phase 4: MFMA(MH1,NH1).  stage: Ub(t+2) -> buf p.  no reads.
    if (n2) { stageA(p, 1, kt + 2); stageA(p, 3, kt + 2); }
    __builtin_amdgcn_s_setprio(1);
    mfma16f<1, 1>(af1, b1, acc);
    __builtin_amdgcn_s_setprio(0);
    __builtin_amdgcn_sched_barrier(0);
    if (n2)      asm volatile("s_waitcnt vmcnt(6)" ::: "memory");
    else if (n1) asm volatile("s_waitcnt vmcnt(0)" ::: "memory");
    SBAR();  // tile boundary: tile t+1 fully staged
  };

  for (int kt = 0; kt < NT_SC; kt += 2) {
    tile(ic<0>{}, kt);
    tile(ic<1>{}, kt + 1);
  }

  // ---- epilogue
#pragma unroll
  for (int mf = 0; mf < 8; ++mf) {
#pragma unroll
    for (int nf = 0; nf < 4; ++nf) {
      const int r0 = brow + wm * 128 + mf * 16 + (lane >> 4) * 4;
      const int c  = bcol + wn * 64 + nf * 16 + (lane & 15);
#pragma unroll
      for (int r = 0; r < 4; ++r)
        C[(size_t)(r0 + r) * N_SEQ + c] = acc[mf][nf][r];
    }
  }
}

// ======================= fused hi/lo split =======================
struct SplitDesc {
  const float* src[7];
  bf16_t* hi[7];
  bf16_t* lo[7];
  int blk_start[8];
};

__global__ __launch_bounds__(256)
void split_all(SplitDesc d)
{
  const int b = blockIdx.x;
  int seg = 0;
#pragma unroll
  for (int s = 1; s < 7; ++s) seg += (b >= d.blk_start[s]) ? 1 : 0;
  const int i = (b - d.blk_start[seg]) * 256 + threadIdx.x;
  const float4 v = ((const float4*)d.src[seg])[i];
  const float vv[4] = {v.x, v.y, v.z, v.w};
  bf16x4 h, l;
#pragma unroll
  for (int j = 0; j < 4; ++j) {
    const bf16_t hh = (bf16_t)vv[j];
    h[j] = hh;
    l[j] = (bf16_t)(vv[j] - (float)hh);
  }
  ((bf16x4*)d.hi[seg])[i] = h;
  if (d.lo[seg]) ((bf16x4*)d.lo[seg])[i] = l;
}

// ======================= softmax =======================
__global__ __launch_bounds__(256)
void softmax_rows(float* __restrict__ S, bf16_t* __restrict__ P, int n)
{
  const int row = blockIdx.x;
  float* srow = S + (size_t)row * n;
  bf16_t* prow = P + (size_t)row * n;
  const int t = threadIdx.x;
  const int lane = t & 63;
  const int wave = t >> 6;
  __shared__ float red[8];

  float4 v[4];
  float mx = -3.4e38f;
#pragma unroll
  for (int i = 0; i < 4; ++i) {
    v[i] = *(const float4*)(srow + (size_t)(i * 256 + t) * 4);
    mx = fmaxf(mx, fmaxf(fmaxf(v[i].x, v[i].y), fmaxf(v[i].z, v[i].w)));
  }
#pragma unroll
  for (int off = 32; off > 0; off >>= 1) mx = fmaxf(mx, __shfl_xor(mx, off));
  if (lane == 0) red[wave] = mx;
  __syncthreads();
  mx = fmaxf(fmaxf(red[0], red[1]), fmaxf(red[2], red[3]));

  float e[16];
  float sum = 0.f;
#pragma unroll
  for (int i = 0; i < 4; ++i) {
    e[4 * i + 0] = __expf(v[i].x - mx);
    e[4 * i + 1] = __expf(v[i].y - mx);
    e[4 * i + 2] = __expf(v[i].z - mx);
    e[4 * i + 3] = __expf(v[i].w - mx);
    sum += e[4 * i + 0] + e[4 * i + 1] + e[4 * i + 2] + e[4 * i + 3];
  }
#pragma unroll
  for (int off = 32; off > 0; off >>= 1) sum += __shfl_xor(sum, off);
  if (lane == 0) red[4 + wave] = sum;
  __syncthreads();
  sum = red[4] + red[5] + red[6] + red[7];
  const float inv = 1.0f / sum;

#pragma unroll
  for (int i = 0; i < 4; ++i) {
    float4 w;
    w.x = e[4 * i + 0] * inv;
    w.y = e[4 * i + 1] * inv;
    w.z = e[4 * i + 2] * inv;
    w.w = e[4 * i + 3] * inv;
    *(float4*)(srow + (size_t)(i * 256 + t) * 4) = w;
    bf16x4 p;
    p[0] = (bf16_t)w.x;
    p[1] = (bf16_t)w.y;
    p[2] = (bf16_t)w.z;
    p[3] = (bf16_t)w.w;
    *(bf16x4*)(prow + (size_t)(i * 256 + t) * 4) = p;
  }
}

extern "C" void kernel_launch(void* const* d_in, const int* in_sizes, int n_in,
                              void* d_out, int out_size, void* d_ws, size_t ws_size,
                              hipStream_t stream) {
  const int N = N_SEQ, D = DMODEL;
  const float* q    = (const float*)d_in[0];
  const float* k    = (const float*)d_in[1];
  const float* v    = (const float*)d_in[2];
  const float* wq_w = (const float*)d_in[3];
  const float* wq_b = (const float*)d_in[4];
  const float* wk_w = (const float*)d_in[5];
  const float* wk_b = (const float*)d_in[6];
  const float* wv_w = (const float*)d_in[7];
  const float* wv_b = (const float*)d_in[8];
  const float* wo_w = (const float*)d_in[9];
  const float* wo_b = (const float*)d_in[10];

  float* x_out = (float*)d_out;                 // [N, D]
  float* attn  = x_out + (size_t)N * D;         // [N, N]

  char* wsp = (char*)d_ws;
  auto alloc = [&](size_t bytes) { char* p = wsp; wsp += bytes; return p; };
  const size_t ND = (size_t)N * D, DD = (size_t)D * D;
  bf16_t* q_hi  = (bf16_t*)alloc(ND * 2);
  bf16_t* q_lo  = (bf16_t*)alloc(ND * 2);
  bf16_t* k_hi  = (bf16_t*)alloc(ND * 2);
  bf16_t* k_lo  = (bf16_t*)alloc(ND * 2);
  bf16_t* v_hi  = (bf16_t*)alloc(ND * 2);
  bf16_t* wq_hi = (bf16_t*)alloc(DD * 2);
  bf16_t* wq_lo = (bf16_t*)alloc(DD * 2);
  bf16_t* wk_hi = (bf16_t*)alloc(DD * 2);
  bf16_t* wk_lo = (bf16_t*)alloc(DD * 2);
  bf16_t* wv_hi = (bf16_t*)alloc(DD * 2);
  bf16_t* wo_hi = (bf16_t*)alloc(DD * 2);
  f16_t*  QPh   = (f16_t*)alloc(ND * 2);        // fp16 qp hi
  f16_t*  QPl   = (f16_t*)alloc(ND * 2);        // fp16 qp lo
  f16_t*  KPh   = (f16_t*)alloc(ND * 2);        // fp16 kp
  bf16_t* spare = (bf16_t*)alloc(ND * 2);       // pad (keeps Pb region 32MB)
  bf16_t* VPt   = (bf16_t*)alloc(ND * 2);       // [D][N] transposed
  // aliases (producers run strictly after last readers of the underlying bufs)
  bf16_t* Pb    = (bf16_t*)QPh;  // 32 MB over QPh..spare
  bf16_t* Xb    = q_hi;          // 8 MB over q_hi
  (void)spare;

  // fused split: q,k -> hi+lo; v -> hi; wq,wk -> hi+lo; wv,wo -> hi
  SplitDesc sd;
  sd.src[0] = q;    sd.hi[0] = q_hi;  sd.lo[0] = q_lo;
  sd.src[1] = k;    sd.hi[1] = k_hi;  sd.lo[1] = k_lo;
  sd.src[2] = v;    sd.hi[2] = v_hi;  sd.lo[2] = nullptr;
  sd.src[3] = wq_w; sd.hi[3] = wq_hi; sd.lo[3] = wq_lo;
  sd.src[4] = wk_w; sd.hi[4] = wk_hi; sd.lo[4] = wk_lo;
  sd.src[5] = wv_w; sd.hi[5] = wv_hi; sd.lo[5] = nullptr;
  sd.src[6] = wo_w; sd.hi[6] = wo_hi; sd.lo[6] = nullptr;
  const int nb_nd = (int)(ND / 4 / 256);   // 4096
  const int nb_dd = (int)(DD / 4 / 256);   // 1024
  sd.blk_start[0] = 0;
  sd.blk_start[1] = nb_nd;
  sd.blk_start[2] = 2 * nb_nd;
  sd.blk_start[3] = 3 * nb_nd;
  sd.blk_start[4] = 3 * nb_nd + nb_dd;
  sd.blk_start[5] = 3 * nb_nd + 2 * nb_dd;
  sd.blk_start[6] = 3 * nb_nd + 3 * nb_dd;
  sd.blk_start[7] = 3 * nb_nd + 4 * nb_dd;
  split_all<<<dim3(sd.blk_start[7]), dim3(256), 0, stream>>>(sd);

  const dim3 blk(256);
  const dim3 gproj(D / BN, N / BM);    // (8, 32)
  const dim3 gsc(N / 256, N / 256);    // (16, 16)

  // Q projection (3-pass hi/lo; epilogue -> fp16 hi/lo split)
  gemm_bt<3, EPI_HILO16><<<gproj, blk, 0, stream>>>(
      q_hi, q_lo, wq_hi, wq_lo, wq_b, nullptr, (bf16_t*)QPh, (bf16_t*)QPl,
      N, D, D);

  // K projection (3-pass; epilogue -> single fp16)
  gemm_bt<3, EPI_F16><<<gproj, blk, 0, stream>>>(
      k_hi, k_lo, wk_hi, wk_lo, wk_b, nullptr, (bf16_t*)KPh, nullptr,
      N, D, D);

  // V projection (1-pass; errors unamplified through softmax-avg)
  gemm_bt<1, EPI_BF16T><<<gproj, blk, 0, stream>>>(
      v_hi, nullptr, wv_hi, nullptr, wv_b, nullptr, VPt, nullptr, N, D, D);

  // scores = (Qh+Ql) @ Kh^T  (fp16 2-pass, R4 structure, logical K=2048)
  gemm8f_scores<<<gsc, dim3(512), 0, stream>>>(QPh, QPl, KPh, attn);

  // softmax rows in-place + bf16 copy (Pb aliases QP/KP region: dead now)
  softmax_rows<<<dim3(N), blk, 0, stream>>>(attn, Pb, N);

  // X = P @ VP
  gemm_bt<1, EPI_BF16><<<gproj, blk, 0, stream>>>(
      Pb, nullptr, VPt, nullptr, nullptr, nullptr, Xb, nullptr, N, D, N);

  // out = X @ wo^T + b
  gemm_bt<1, EPI_F32><<<gproj, blk, 0, stream>>>(
      Xb, nullptr, wo_hi, nullptr, wo_b, x_out, nullptr, nullptr, N, D, D);
}

// Round 7
// 273.391 us; speedup vs baseline: 1.5718x; 1.3113x over previous
//
#include <hip/hip_runtime.h>
#include <cstdint>

// Problem constants (fixed by the reference)
#define N_SEQ 4096
#define DMODEL 1024

#define BM 128
#define BN 128
#define BK 32

typedef __bf16 bf16_t;
typedef _Float16 f16_t;
typedef bf16_t bf16x8 __attribute__((ext_vector_type(8)));
typedef bf16_t bf16x4 __attribute__((ext_vector_type(4)));
typedef f16_t f16x8 __attribute__((ext_vector_type(8)));
typedef float f32x4 __attribute__((ext_vector_type(4)));

typedef __attribute__((address_space(1))) void* as1ptr;
typedef __attribute__((address_space(3))) void* as3ptr;

__device__ __forceinline__ void gload16(const void* g, void* l) {
  __builtin_amdgcn_global_load_lds((as1ptr)(uintptr_t)g, (as3ptr)(uintptr_t)l,
                                   16, 0, 0);
}

// ================= fused QKV projection (z = 0:Q, 1:K, 2:V) =================
// z=0: qp = q@wq^T+b -> fp16 hi/lo      (3-pass hi/lo bf16 GEMM)
// z=1: kp = k@wk^T+b -> fp16            (3-pass)
// z=2: vp = v@wv^T+b -> bf16 transposed (1-pass)
// grid (8, 32, 3) = 768 blocks -> ~3 blocks/CU (vs 1 for separate launches).
__global__ __launch_bounds__(256)
void qkv_proj(const bf16_t* __restrict__ q_hi, const bf16_t* __restrict__ q_lo,
              const bf16_t* __restrict__ wq_hi, const bf16_t* __restrict__ wq_lo,
              const float* __restrict__ wq_b,
              const bf16_t* __restrict__ k_hi, const bf16_t* __restrict__ k_lo,
              const bf16_t* __restrict__ wk_hi, const bf16_t* __restrict__ wk_lo,
              const float* __restrict__ wk_b,
              const bf16_t* __restrict__ v_hi, const bf16_t* __restrict__ wv_hi,
              const float* __restrict__ wv_b,
              f16_t* __restrict__ QPh, f16_t* __restrict__ QPl,
              f16_t* __restrict__ KPh, bf16_t* __restrict__ VPt)
{
  __shared__ __align__(16) bf16_t lds[4 * BM * BK];   // 32 KiB
  bf16_t* lAhi = lds;
  bf16_t* lBhi = lds + BM * BK;
  bf16_t* lAlo = lds + 2 * BM * BK;
  bf16_t* lBlo = lds + 3 * BM * BK;

  const int z = blockIdx.z;
  const bf16_t *Ahi, *Alo = nullptr, *Bhi, *Blo = nullptr;
  const float* bias;
  bool three;
  if (z == 0)      { Ahi = q_hi; Alo = q_lo; Bhi = wq_hi; Blo = wq_lo; bias = wq_b; three = true; }
  else if (z == 1) { Ahi = k_hi; Alo = k_lo; Bhi = wk_hi; Blo = wk_lo; bias = wk_b; three = true; }
  else             { Ahi = v_hi;              Bhi = wv_hi;              bias = wv_b; three = false; }

  const int M = N_SEQ, Nc = DMODEL, K = DMODEL;
  const int t = threadIdx.x;
  const int lane = t & 63;
  const int wave = t >> 6;
  const int wm = wave >> 1;
  const int wn = wave & 1;
  const int row0 = blockIdx.y * BM;
  const int col0 = blockIdx.x * BN;

  const int srow = t >> 2;
  const int scol = (t & 3) * 8;
  const int loff = srow * BK + scol;

  const int fr = lane & 15;
  const int kq = (lane >> 4) * 8;

  f32x4 acc[4][4] = {};

  for (int k0 = 0; k0 < K; k0 += BK) {
    const size_t ga = (size_t)(row0 + srow) * K + k0 + scol;
    const size_t gb = (size_t)(col0 + srow) * K + k0 + scol;
    gload16(Ahi + ga, lAhi + loff);
    gload16(Ahi + ga + (size_t)64 * K, lAhi + loff + 64 * BK);
    gload16(Bhi + gb, lBhi + loff);
    gload16(Bhi + gb + (size_t)64 * K, lBhi + loff + 64 * BK);
    if (three) {
      gload16(Alo + ga, lAlo + loff);
      gload16(Alo + ga + (size_t)64 * K, lAlo + loff + 64 * BK);
      gload16(Blo + gb, lBlo + loff);
      gload16(Blo + gb + (size_t)64 * K, lBlo + loff + 64 * BK);
    }
    __syncthreads();

    bf16x8 ah[4], bh[4], al[4], bl[4];
#pragma unroll
    for (int m = 0; m < 4; ++m)
      ah[m] = *(const bf16x8*)&lAhi[(wm * 64 + m * 16 + fr) * BK + kq];
#pragma unroll
    for (int n = 0; n < 4; ++n)
      bh[n] = *(const bf16x8*)&lBhi[(wn * 64 + n * 16 + fr) * BK + kq];
    if (three) {
#pragma unroll
      for (int m = 0; m < 4; ++m)
        al[m] = *(const bf16x8*)&lAlo[(wm * 64 + m * 16 + fr) * BK + kq];
#pragma unroll
      for (int n = 0; n < 4; ++n)
        bl[n] = *(const bf16x8*)&lBlo[(wn * 64 + n * 16 + fr) * BK + kq];
    }

#pragma unroll
    for (int m = 0; m < 4; ++m)
#pragma unroll
      for (int n = 0; n < 4; ++n) {
        acc[m][n] =
            __builtin_amdgcn_mfma_f32_16x16x32_bf16(ah[m], bh[n], acc[m][n], 0, 0, 0);
        if (three) {
          acc[m][n] =
              __builtin_amdgcn_mfma_f32_16x16x32_bf16(ah[m], bl[n], acc[m][n], 0, 0, 0);
          acc[m][n] =
              __builtin_amdgcn_mfma_f32_16x16x32_bf16(al[m], bh[n], acc[m][n], 0, 0, 0);
        }
      }
    __syncthreads();
  }

#pragma unroll
  for (int m = 0; m < 4; ++m) {
#pragma unroll
    for (int n = 0; n < 4; ++n) {
      const int grow0 = row0 + wm * 64 + m * 16 + (lane >> 4) * 4;
      const int gcol = col0 + wn * 64 + n * 16 + (lane & 15);
      const float bv = bias[gcol];
      if (z == 2) {
        bf16x4 p;
#pragma unroll
        for (int r = 0; r < 4; ++r) p[r] = (bf16_t)(acc[m][n][r] + bv);
        *(bf16x4*)&VPt[(size_t)gcol * M + grow0] = p;
      } else if (z == 0) {
#pragma unroll
        for (int r = 0; r < 4; ++r) {
          const float val = acc[m][n][r] + bv;
          const size_t idx = (size_t)(grow0 + r) * Nc + gcol;
          const f16_t h = (f16_t)val;
          QPh[idx] = h;
          QPl[idx] = (f16_t)(val - (float)h);
        }
      } else {
#pragma unroll
        for (int r = 0; r < 4; ++r) {
          const float val = acc[m][n][r] + bv;
          KPh[(size_t)(grow0 + r) * Nc + gcol] = (f16_t)val;
        }
      }
    }
  }
}

// ================= split-K bf16 GEMM -> fp32 partials =================
// C_part[z][M,Nc] = A[M, kbeg:kend] @ B[Nc, kbeg:kend]^T   (z = blockIdx.z)
__global__ __launch_bounds__(256)
void gemm_sk(const bf16_t* __restrict__ A, const bf16_t* __restrict__ B,
             float* __restrict__ Part, int M, int Nc, int K, int kspl)
{
  __shared__ __align__(16) bf16_t lds[2 * BM * BK];   // 16 KiB
  bf16_t* lA = lds;
  bf16_t* lB = lds + BM * BK;

  float* out = Part + (size_t)blockIdx.z * M * Nc;
  const int kbeg = blockIdx.z * kspl;
  const int kend = kbeg + kspl;

  const int t = threadIdx.x;
  const int lane = t & 63;
  const int wave = t >> 6;
  const int wm = wave >> 1;
  const int wn = wave & 1;
  const int row0 = blockIdx.y * BM;
  const int col0 = blockIdx.x * BN;

  const int srow = t >> 2;
  const int scol = (t & 3) * 8;
  const int loff = srow * BK + scol;

  const int fr = lane & 15;
  const int kq = (lane >> 4) * 8;

  f32x4 acc[4][4] = {};

  for (int k0 = kbeg; k0 < kend; k0 += BK) {
    const size_t ga = (size_t)(row0 + srow) * K + k0 + scol;
    const size_t gb = (size_t)(col0 + srow) * K + k0 + scol;
    gload16(A + ga, lA + loff);
    gload16(A + ga + (size_t)64 * K, lA + loff + 64 * BK);
    gload16(B + gb, lB + loff);
    gload16(B + gb + (size_t)64 * K, lB + loff + 64 * BK);
    __syncthreads();

    bf16x8 ah[4], bh[4];
#pragma unroll
    for (int m = 0; m < 4; ++m)
      ah[m] = *(const bf16x8*)&lA[(wm * 64 + m * 16 + fr) * BK + kq];
#pragma unroll
    for (int n = 0; n < 4; ++n)
      bh[n] = *(const bf16x8*)&lB[(wn * 64 + n * 16 + fr) * BK + kq];

#pragma unroll
    for (int m = 0; m < 4; ++m)
#pragma unroll
      for (int n = 0; n < 4; ++n)
        acc[m][n] =
            __builtin_amdgcn_mfma_f32_16x16x32_bf16(ah[m], bh[n], acc[m][n], 0, 0, 0);
    __syncthreads();
  }

#pragma unroll
  for (int m = 0; m < 4; ++m) {
#pragma unroll
    for (int n = 0; n < 4; ++n) {
      const int grow0 = row0 + wm * 64 + m * 16 + (lane >> 4) * 4;
      const int gcol = col0 + wn * 64 + n * 16 + (lane & 15);
#pragma unroll
      for (int r = 0; r < 4; ++r)
        out[(size_t)(grow0 + r) * Nc + gcol] = acc[m][n][r];
    }
  }
}

// partial reducers
__global__ __launch_bounds__(256)
void reduce_bf16(const float4* __restrict__ p0, const float4* __restrict__ p1,
                 bf16x4* __restrict__ out, int n4)
{
  const int i = blockIdx.x * 256 + threadIdx.x;
  if (i >= n4) return;
  const float4 a = p0[i], b = p1[i];
  bf16x4 r;
  r[0] = (bf16_t)(a.x + b.x);
  r[1] = (bf16_t)(a.y + b.y);
  r[2] = (bf16_t)(a.z + b.z);
  r[3] = (bf16_t)(a.w + b.w);
  out[i] = r;
}

__global__ __launch_bounds__(256)
void reduce_out(const float4* __restrict__ p0, const float4* __restrict__ p1,
                const float* __restrict__ bias, float4* __restrict__ out, int n4)
{
  const int i = blockIdx.x * 256 + threadIdx.x;
  if (i >= n4) return;
  const float4 a = p0[i], b = p1[i];
  const int col = (i * 4) & (DMODEL - 1);
  const float4 bb = *(const float4*)(bias + col);
  float4 r;
  r.x = a.x + b.x + bb.x;
  r.y = a.y + b.y + bb.y;
  r.z = a.z + b.z + bb.z;
  r.w = a.w + b.w + bb.w;
  out[i] = r;
}

// ============ fp16 2-pass 256x256 scores GEMM (R4 structure) ============
// scores = (Qh+Ql) @ Kh^T as single-pass fp16 GEMM with logical K = 2*1024:
// kt 0-15 -> Qh*Kh, kt 16-31 -> Ql*Kh.  LDS: 2 mats x 2 bufs = 128 KiB.
#define TILE_ELEMS 16384   // 256 rows x 64 cols
#define UNIT_ELEMS 4096    // 64 rows x 64 cols
#define NT_SC 32

template <int V> struct ic { static constexpr int value = V; };

#define SBAR() asm volatile("s_barrier" ::: "memory")
#define WAITLGKM(n)                                              \
  do {                                                           \
    asm volatile("s_waitcnt lgkmcnt(" #n ")" ::: "memory");      \
    __builtin_amdgcn_sched_barrier(0);                           \
  } while (0)

template <int MH>
__device__ __forceinline__ void load_A8f(const f16_t* Ab, int wm, int fr,
                                         int kq, int sw, f16x8 (&af)[4][2]) {
#pragma unroll
  for (int m = 0; m < 4; ++m) {
    const int row = wm * 128 + (MH * 4 + m) * 16 + fr;
#pragma unroll
    for (int ks = 0; ks < 2; ++ks)
      af[m][ks] = *(const f16x8*)&Ab[row * 64 + ((ks * 32 + kq) ^ sw)];
  }
}

template <int NH>
__device__ __forceinline__ void load_B4f(const f16_t* Bb, int wn, int fr,
                                         int kq, int sw, f16x8 (&bfr)[2][2]) {
#pragma unroll
  for (int n = 0; n < 2; ++n) {
    const int row = wn * 64 + (NH * 2 + n) * 16 + fr;
#pragma unroll
    for (int ks = 0; ks < 2; ++ks)
      bfr[n][ks] = *(const f16x8*)&Bb[row * 64 + ((ks * 32 + kq) ^ sw)];
  }
}

template <int MH, int NH>
__device__ __forceinline__ void mfma16f(const f16x8 (&af)[4][2],
                                        const f16x8 (&bfr)[2][2],
                                        f32x4 (&acc)[8][4]) {
#pragma unroll
  for (int m = 0; m < 4; ++m)
#pragma unroll
    for (int n = 0; n < 2; ++n)
#pragma unroll
      for (int ks = 0; ks < 2; ++ks)
        acc[MH * 4 + m][NH * 2 + n] = __builtin_amdgcn_mfma_f32_16x16x32_f16(
            af[m][ks], bfr[n][ks], acc[MH * 4 + m][NH * 2 + n], 0, 0, 0);
}

__global__ __launch_bounds__(512, 2)
void gemm8f_scores(const f16_t* __restrict__ Qh, const f16_t* __restrict__ Ql,
                   const f16_t* __restrict__ Kh, float* __restrict__ C)
{
  __shared__ __align__(16) f16_t sm[2 * 2 * TILE_ELEMS];  // 128 KiB

  const int t = threadIdx.x;
  const int lane = t & 63;
  const int wave = t >> 6;
  const int wm = wave >> 2;      // 0..1
  const int wn = wave & 3;       // 0..3

  // XCD-aware block swizzle: grid 16x16 = 256 blocks, 256 = 8*32 (bijective)
  const int flat = blockIdx.y * 16 + blockIdx.x;
  const int swzb = (flat & 7) * 32 + (flat >> 3);
  const int brow = (swzb >> 4) * 256;
  const int bcol = (swzb & 15) * 256;

  const int srow = t >> 3;                               // 0..63
  const int scol = 8 * ((t & 7) ^ ((t >> 3) & 7));       // involution
  const int sdst = t * 8;

  const int fr = lane & 15;
  const int kq = (lane >> 4) * 8;
  const int sw = (fr & 7) << 3;                          // read-side swizzle

  auto stageA = [&](int buf, int u, int kt) {
    const f16_t* src = (kt >= 16) ? Ql : Qh;
    const int kk = (kt & 15) << 6;
    gload16(src + (size_t)(brow + u * 64 + srow) * DMODEL + kk + scol,
            &sm[(buf * 2 + 0) * TILE_ELEMS + u * UNIT_ELEMS + sdst]);
  };
  auto stageB = [&](int buf, int u, int kt) {
    const int kk = (kt & 15) << 6;
    gload16(Kh + (size_t)(bcol + u * 64 + srow) * DMODEL + kk + scol,
            &sm[(buf * 2 + 1) * TILE_ELEMS + u * UNIT_ELEMS + sdst]);
  };

  f32x4 acc[8][4] = {};
  f16x8 af0[4][2], af1[4][2];
  f16x8 b0[2][2], b1[2][2];

  // ---- prologue: tile0 all 8 units; tile1's Ua, V01, Ub (6 loads).
#pragma unroll
  for (int u = 0; u < 4; ++u) stageA(0, u, 0);
#pragma unroll
  for (int u = 0; u < 4; ++u) stageB(0, u, 0);
  stageA(1, 0, 1); stageA(1, 2, 1);   // Ua(1)
  stageB(1, 0, 1); stageB(1, 1, 1);   // V01(1)
  stageA(1, 1, 1); stageA(1, 3, 1);   // Ub(1)
  asm volatile("s_waitcnt vmcnt(6)" ::: "memory");  // tile0's 8 landed
  SBAR();

  auto tile = [&](auto Pc, int kt) {
    constexpr int p = decltype(Pc)::value;
    constexpr int q = p ^ 1;
    const bool n1 = (kt + 1 < NT_SC);
    const bool n2 = (kt + 2 < NT_SC);
    const f16_t* Ab = &sm[(p * 2 + 0) * TILE_ELEMS];
    const f16_t* Bb = &sm[(p * 2 + 1) * TILE_ELEMS];

    // ---- Phase 1
    load_A8f<0>(Ab, wm, fr, kq, sw, af0);
    load_B4f<0>(Bb, wn, fr, kq, sw, b0);
    if (n1) { stageB(q, 2, kt + 1); stageB(q, 3, kt + 1); }
    load_B4f<1>(Bb, wn, fr, kq, sw, b1);
    WAITLGKM(4);
    __builtin_amdgcn_s_setprio(1);
    mfma16f<0, 0>(af0, b0, acc);
    __builtin_amdgcn_s_setprio(0);
    __builtin_amdgcn_sched_barrier(0);
    SBAR();

    // ---- Phase 2
    if (n2) { stageA(p, 0, kt + 2); stageA(p, 2, kt + 2); }
    load_A8f<1>(Ab, wm, fr, kq, sw, af1);
    WAITLGKM(8);
    __builtin_amdgcn_s_setprio(1);
    mfma16f<0, 1>(af0, b1, acc);
    __builtin_amdgcn_s_setprio(0);
    __builtin_amdgcn_sched_barrier(0);
    SBAR();

    // ---- Phase 3
    if (n2) { stageB(p, 0, kt + 2); stageB(p, 1, kt + 2); }
    WAITLGKM(0);
    __builtin_amdgcn_s_setprio(1);
    mfma16f<1, 0>(af1, b0, acc);
    __builtin_amdgcn_s_setprio(0);
    __builtin_amdgcn_sched_barrier(0);
    SBAR();

    // ---- Phase 4
    if (n2) { stageA(p, 1, kt + 2); stageA(p, 3, kt + 2); }
    __builtin_amdgcn_s_setprio(1);
    mfma16f<1, 1>(af1, b1, acc);
    __builtin_amdgcn_s_setprio(0);
    __builtin_amdgcn_sched_barrier(0);
    if (n2)      asm volatile("s_waitcnt vmcnt(6)" ::: "memory");
    else if (n1) asm volatile("s_waitcnt vmcnt(0)" ::: "memory");
    SBAR();
  };

  for (int kt = 0; kt < NT_SC; kt += 2) {
    tile(ic<0>{}, kt);
    tile(ic<1>{}, kt + 1);
  }

  // ---- epilogue
#pragma unroll
  for (int mf = 0; mf < 8; ++mf) {
#pragma unroll
    for (int nf = 0; nf < 4; ++nf) {
      const int r0 = brow + wm * 128 + mf * 16 + (lane >> 4) * 4;
      const int c  = bcol + wn * 64 + nf * 16 + (lane & 15);
#pragma unroll
      for (int r = 0; r < 4; ++r)
        C[(size_t)(r0 + r) * N_SEQ + c] = acc[mf][nf][r];
    }
  }
}

// ======================= fused hi/lo split =======================
struct SplitDesc {
  const float* src[7];
  bf16_t* hi[7];
  bf16_t* lo[7];
  int blk_start[8];
};

__global__ __launch_bounds__(256)
void split_all(SplitDesc d)
{
  const int b = blockIdx.x;
  int seg = 0;
#pragma unroll
  for (int s = 1; s < 7; ++s) seg += (b >= d.blk_start[s]) ? 1 : 0;
  const int i = (b - d.blk_start[seg]) * 256 + threadIdx.x;
  const float4 v = ((const float4*)d.src[seg])[i];
  const float vv[4] = {v.x, v.y, v.z, v.w};
  bf16x4 h, l;
#pragma unroll
  for (int j = 0; j < 4; ++j) {
    const bf16_t hh = (bf16_t)vv[j];
    h[j] = hh;
    l[j] = (bf16_t)(vv[j] - (float)hh);
  }
  ((bf16x4*)d.hi[seg])[i] = h;
  if (d.lo[seg]) ((bf16x4*)d.lo[seg])[i] = l;
}

// ======================= softmax =======================
__global__ __launch_bounds__(256)
void softmax_rows(float* __restrict__ S, bf16_t* __restrict__ P, int n)
{
  const int row = blockIdx.x;
  float* srow = S + (size_t)row * n;
  bf16_t* prow = P + (size_t)row * n;
  const int t = threadIdx.x;
  const int lane = t & 63;
  const int wave = t >> 6;
  __shared__ float red[8];

  float4 v[4];
  float mx = -3.4e38f;
#pragma unroll
  for (int i = 0; i < 4; ++i) {
    v[i] = *(const float4*)(srow + (size_t)(i * 256 + t) * 4);
    mx = fmaxf(mx, fmaxf(fmaxf(v[i].x, v[i].y), fmaxf(v[i].z, v[i].w)));
  }
#pragma unroll
  for (int off = 32; off > 0; off >>= 1) mx = fmaxf(mx, __shfl_xor(mx, off));
  if (lane == 0) red[wave] = mx;
  __syncthreads();
  mx = fmaxf(fmaxf(red[0], red[1]), fmaxf(red[2], red[3]));

  float e[16];
  float sum = 0.f;
#pragma unroll
  for (int i = 0; i < 4; ++i) {
    e[4 * i + 0] = __expf(v[i].x - mx);
    e[4 * i + 1] = __expf(v[i].y - mx);
    e[4 * i + 2] = __expf(v[i].z - mx);
    e[4 * i + 3] = __expf(v[i].w - mx);
    sum += e[4 * i + 0] + e[4 * i + 1] + e[4 * i + 2] + e[4 * i + 3];
  }
#pragma unroll
  for (int off = 32; off > 0; off >>= 1) sum += __shfl_xor(sum, off);
  if (lane == 0) red[4 + wave] = sum;
  __syncthreads();
  sum = red[4] + red[5] + red[6] + red[7];
  const float inv = 1.0f / sum;

#pragma unroll
  for (int i = 0; i < 4; ++i) {
    float4 w;
    w.x = e[4 * i + 0] * inv;
    w.y = e[4 * i + 1] * inv;
    w.z = e[4 * i + 2] * inv;
    w.w = e[4 * i + 3] * inv;
    *(float4*)(srow + (size_t)(i * 256 + t) * 4) = w;
    bf16x4 p;
    p[0] = (bf16_t)w.x;
    p[1] = (bf16_t)w.y;
    p[2] = (bf16_t)w.z;
    p[3] = (bf16_t)w.w;
    *(bf16x4*)(prow + (size_t)(i * 256 + t) * 4) = p;
  }
}

extern "C" void kernel_launch(void* const* d_in, const int* in_sizes, int n_in,
                              void* d_out, int out_size, void* d_ws, size_t ws_size,
                              hipStream_t stream) {
  const int N = N_SEQ, D = DMODEL;
  const float* q    = (const float*)d_in[0];
  const float* k    = (const float*)d_in[1];
  const float* v    = (const float*)d_in[2];
  const float* wq_w = (const float*)d_in[3];
  const float* wq_b = (const float*)d_in[4];
  const float* wk_w = (const float*)d_in[5];
  const float* wk_b = (const float*)d_in[6];
  const float* wv_w = (const float*)d_in[7];
  const float* wv_b = (const float*)d_in[8];
  const float* wo_w = (const float*)d_in[9];
  const float* wo_b = (const float*)d_in[10];

  float* x_out = (float*)d_out;                 // [N, D]
  float* attn  = x_out + (size_t)N * D;         // [N, N]

  char* wsp = (char*)d_ws;
  auto alloc = [&](size_t bytes) { char* p = wsp; wsp += bytes; return p; };
  const size_t ND = (size_t)N * D, DD = (size_t)D * D;
  bf16_t* q_hi  = (bf16_t*)alloc(ND * 2);
  bf16_t* q_lo  = (bf16_t*)alloc(ND * 2);
  bf16_t* k_hi  = (bf16_t*)alloc(ND * 2);
  bf16_t* k_lo  = (bf16_t*)alloc(ND * 2);
  bf16_t* v_hi  = (bf16_t*)alloc(ND * 2);
  bf16_t* wq_hi = (bf16_t*)alloc(DD * 2);
  bf16_t* wq_lo = (bf16_t*)alloc(DD * 2);
  bf16_t* wk_hi = (bf16_t*)alloc(DD * 2);
  bf16_t* wk_lo = (bf16_t*)alloc(DD * 2);
  bf16_t* wv_hi = (bf16_t*)alloc(DD * 2);
  bf16_t* wo_hi = (bf16_t*)alloc(DD * 2);
  f16_t*  QPh   = (f16_t*)alloc(ND * 2);        // fp16 qp hi
  f16_t*  QPl   = (f16_t*)alloc(ND * 2);        // fp16 qp lo
  f16_t*  KPh   = (f16_t*)alloc(ND * 2);        // fp16 kp
  bf16_t* spare = (bf16_t*)alloc(ND * 2);       // pad (keeps Pb region 32MB)
  bf16_t* VPt   = (bf16_t*)alloc(ND * 2);       // [D][N] transposed
  // aliases (producers run strictly after last readers of the underlying bufs)
  bf16_t* Pb    = (bf16_t*)QPh;  // 32 MB over QPh..spare (dead after scores)
  bf16_t* Xb    = q_hi;          // 8 MB over q_hi (dead after qkv_proj)
  float*  Part  = (float*)q_lo;  // 33.6 MB over q_lo..wq_hi (dead after qkv_proj)
  (void)spare;

  // fused split: q,k -> hi+lo; v -> hi; wq,wk -> hi+lo; wv,wo -> hi
  SplitDesc sd;
  sd.src[0] = q;    sd.hi[0] = q_hi;  sd.lo[0] = q_lo;
  sd.src[1] = k;    sd.hi[1] = k_hi;  sd.lo[1] = k_lo;
  sd.src[2] = v;    sd.hi[2] = v_hi;  sd.lo[2] = nullptr;
  sd.src[3] = wq_w; sd.hi[3] = wq_hi; sd.lo[3] = wq_lo;
  sd.src[4] = wk_w; sd.hi[4] = wk_hi; sd.lo[4] = wk_lo;
  sd.src[5] = wv_w; sd.hi[5] = wv_hi; sd.lo[5] = nullptr;
  sd.src[6] = wo_w; sd.hi[6] = wo_hi; sd.lo[6] = nullptr;
  const int nb_nd = (int)(ND / 4 / 256);   // 4096
  const int nb_dd = (int)(DD / 4 / 256);   // 1024
  sd.blk_start[0] = 0;
  sd.blk_start[1] = nb_nd;
  sd.blk_start[2] = 2 * nb_nd;
  sd.blk_start[3] = 3 * nb_nd;
  sd.blk_start[4] = 3 * nb_nd + nb_dd;
  sd.blk_start[5] = 3 * nb_nd + 2 * nb_dd;
  sd.blk_start[6] = 3 * nb_nd + 3 * nb_dd;
  sd.blk_start[7] = 3 * nb_nd + 4 * nb_dd;
  split_all<<<dim3(sd.blk_start[7]), dim3(256), 0, stream>>>(sd);

  const dim3 blk(256);
  const dim3 gsc(N / 256, N / 256);    // (16, 16)
  const int n4 = (int)(ND / 4);        // 1048576
  const dim3 gred((n4 + 255) / 256);

  // fused Q/K/V projections: grid (8,32,3) -> 3 blocks/CU
  qkv_proj<<<dim3(D / BN, N / BM, 3), blk, 0, stream>>>(
      q_hi, q_lo, wq_hi, wq_lo, wq_b,
      k_hi, k_lo, wk_hi, wk_lo, wk_b,
      v_hi, wv_hi, wv_b,
      QPh, QPl, KPh, VPt);

  // scores = (Qh+Ql) @ Kh^T  (fp16 2-pass, logical K=2048)
  gemm8f_scores<<<gsc, dim3(512), 0, stream>>>(QPh, QPl, KPh, attn);

  // softmax rows in-place + bf16 copy (Pb aliases QP/KP region: dead now)
  softmax_rows<<<dim3(N), blk, 0, stream>>>(attn, Pb, N);

  // X = P @ VP  (split-K=2 -> fp32 partials -> bf16 Xb)
  gemm_sk<<<dim3(D / BN, N / BM, 2), blk, 0, stream>>>(
      Pb, VPt, Part, N, D, N, N / 2);
  reduce_bf16<<<gred, blk, 0, stream>>>(
      (const float4*)Part, (const float4*)(Part + ND), (bf16x4*)Xb, n4);

  // out = X @ wo^T + b  (split-K=2 -> fp32 partials -> +bias -> d_out)
  gemm_sk<<<dim3(D / BN, N / BM, 2), blk, 0, stream>>>(
      Xb, wo_hi, Part, N, D, D, D / 2);
  reduce_out<<<gred, blk, 0, stream>>>(
      (const float4*)Part, (const float4*)(Part + ND), wo_b,
      (float4*)x_out, n4);
}